// Round 2
// baseline (950.281 us; speedup 1.0000x reference)
//
#include <hip/hip_runtime.h>

// DBRX MoE experts forward, MI355X gfx950.
// T=2048 tokens, H=1024, F=2048, E=8, K=2.
// Storage dtypes (per reference): ALL float tensors are f32; top_experts int
// (int64 in reference; probe handles int64-vs-int32 storage). Output f32.
// Compute: bf16 MFMA with f32 accumulate. Dense-over-experts (cw[e][t]
// combine matrix, zero for unrouted pairs) -> two MFMA NT-GEMMs per expert.

#define T_ 2048
#define H_ 1024
#define F_ 2048
#define E_ 8

typedef unsigned short u16;
typedef short s8v __attribute__((ext_vector_type(8)));
typedef float f4v __attribute__((ext_vector_type(4)));
typedef unsigned short u16x4 __attribute__((ext_vector_type(4)));

__device__ __forceinline__ u16 f2bf(float f) {
    union { float f; unsigned u; } v; v.f = f;
    unsigned r = v.u + 0x7FFF + ((v.u >> 16) & 1);   // RNE
    return (u16)(r >> 16);
}

// ---------------------------------------------------------------------------
// top_experts storage probe: if stored int64, odd int32 words (hi-words of
// values 0..7) are ALL zero; if int32, odd words are slot-1 expert ids
// (nonzero somewhere over 2048 tokens). flag=1 -> int32, flag=0 -> int64.
__global__ void detect_kernel(const int* __restrict__ te, int* __restrict__ flag) {
    __shared__ int s;
    if (threadIdx.x == 0) s = 0;
    __syncthreads();
    int any = 0;
    for (int i = threadIdx.x; i < 2 * T_; i += 256)
        if (i & 1) any |= te[i];
    if (any) atomicOr(&s, 1);
    __syncthreads();
    if (threadIdx.x == 0) *flag = (s != 0) ? 1 : 0;
}

// cw[e][t] = sum_k top_weights[t,k] * (top_experts[t,k]==e)
__global__ void cw_kernel(const int* __restrict__ te, const float* __restrict__ tw,
                          const int* __restrict__ flag, float* __restrict__ cw) {
    int t = blockIdx.x * 256 + threadIdx.x;
    if (t >= T_) return;
    bool is32 = (*flag != 0);
    int e0 = is32 ? te[2 * t]     : te[4 * t];
    int e1 = is32 ? te[2 * t + 1] : te[4 * t + 2];
    float w0 = tw[2 * t];
    float w1 = tw[2 * t + 1];
#pragma unroll
    for (int e = 0; e < E_; ++e)
        cw[e * T_ + t] = (e == e0 ? w0 : 0.f) + (e == e1 ? w1 : 0.f);
}

// ---------------------------------------------------------------------------
// f32 -> bf16 elementwise, 4 elems/thread. n must be multiple of 1024.
__global__ void cvt_kernel(const float* __restrict__ src, u16* __restrict__ dst) {
    int i = (blockIdx.x * 256 + threadIdx.x) * 4;
    float4 v = *(const float4*)(src + i);
    u16x4 o = { f2bf(v.x), f2bf(v.y), f2bf(v.z), f2bf(v.w) };
    *(u16x4*)(dst + i) = o;
}

// f32 [R][C] -> bf16 [C][R] transpose+convert, 64x64 tiles, block (8,32).
__global__ void tcvt_kernel(const float* __restrict__ src, u16* __restrict__ dst,
                            int R, int C) {
    __shared__ __align__(16) u16 tile[64][72];   // 72*2=144B row stride, 16B-aligned
    int bc = blockIdx.x * 64, br = blockIdx.y * 64;
    int tx = threadIdx.x;          // 0..7  -> 8-elem chunks
    int ty = threadIdx.y;          // 0..31
    for (int r = ty; r < 64; r += 32) {
        const float* p = src + (size_t)(br + r) * C + bc + tx * 8;
        float4 v0 = *(const float4*)p;
        float4 v1 = *(const float4*)(p + 4);
        u16* q = &tile[r][tx * 8];
        q[0] = f2bf(v0.x); q[1] = f2bf(v0.y); q[2] = f2bf(v0.z); q[3] = f2bf(v0.w);
        q[4] = f2bf(v1.x); q[5] = f2bf(v1.y); q[6] = f2bf(v1.z); q[7] = f2bf(v1.w);
    }
    __syncthreads();
    for (int c = ty; c < 64; c += 32) {
        u16 tmp[8];
#pragma unroll
        for (int j = 0; j < 8; ++j) tmp[j] = tile[tx * 8 + j][c];
        *(int4*)&dst[(size_t)(bc + c) * R + br + tx * 8] = *(int4*)tmp;
    }
}

// ---------------------------------------------------------------------------
// GEMM 1 (fused GLU): g[t][f] = sum_h xb[t][h]*w1e[f][h]; u likewise (v1e).
//   inter[t][f] = bf16( cw[t] * silu(g) * u )
// 128x128 tile, BK=32, 4 waves (2x2), 4x4 16x16 frags/wave, dual accumulators.
// MFMA bf16 16x16x32 layouts (guide-verified):
//   A/B operand: m|n = lane&15, k = (lane>>4)*8 + j
//   C/D: col(N) = lane&15, row(M) = (lane>>4)*4 + reg
__global__ __launch_bounds__(256) void gemm_glu_kernel(
        const u16* __restrict__ xb,   // [T][H] bf16
        const u16* __restrict__ w1e,  // [F][H] bf16
        const u16* __restrict__ v1e,  // [F][H] bf16
        const float* __restrict__ cwe,// [T]
        u16* __restrict__ inter) {    // [T][F] bf16
    __shared__ __align__(16) u16 As[128 * 32];
    __shared__ __align__(16) u16 B1s[128 * 32];
    __shared__ __align__(16) u16 B2s[128 * 32];
    int tid = threadIdx.x;
    int lane = tid & 63, wave = tid >> 6;
    int wm = wave >> 1, wn = wave & 1;
    int t0 = blockIdx.x * 128, f0 = blockIdx.y * 128;
    int ml = lane & 15, q = lane >> 4;

    f4v accg[4][4] = {};
    f4v accu[4][4] = {};

    const u16* ga  = xb  + (size_t)t0 * H_;
    const u16* gb1 = w1e + (size_t)f0 * H_;
    const u16* gb2 = v1e + (size_t)f0 * H_;

    for (int k0 = 0; k0 < H_; k0 += 32) {
        __syncthreads();
#pragma unroll
        for (int p = 0; p < 2; ++p) {
            int c = p * 256 + tid;
            int r = c >> 2, co = (c & 3) * 8;
            *(int4*)(As  + c * 8) = *(const int4*)(ga  + (size_t)r * H_ + k0 + co);
            *(int4*)(B1s + c * 8) = *(const int4*)(gb1 + (size_t)r * H_ + k0 + co);
            *(int4*)(B2s + c * 8) = *(const int4*)(gb2 + (size_t)r * H_ + k0 + co);
        }
        __syncthreads();
        s8v a[4], b1[4], b2[4];
#pragma unroll
        for (int i = 0; i < 4; ++i) {
            a[i]  = *(const s8v*)(As  + (wm * 64 + i * 16 + ml) * 32 + q * 8);
            b1[i] = *(const s8v*)(B1s + (wn * 64 + i * 16 + ml) * 32 + q * 8);
            b2[i] = *(const s8v*)(B2s + (wn * 64 + i * 16 + ml) * 32 + q * 8);
        }
#pragma unroll
        for (int i = 0; i < 4; ++i)
#pragma unroll
            for (int j = 0; j < 4; ++j) {
                accg[i][j] = __builtin_amdgcn_mfma_f32_16x16x32_bf16(a[i], b1[j], accg[i][j], 0, 0, 0);
                accu[i][j] = __builtin_amdgcn_mfma_f32_16x16x32_bf16(a[i], b2[j], accu[i][j], 0, 0, 0);
            }
    }
#pragma unroll
    for (int i = 0; i < 4; ++i) {
#pragma unroll
        for (int r = 0; r < 4; ++r) {
            int t = t0 + wm * 64 + i * 16 + q * 4 + r;
            float cv = cwe[t];
#pragma unroll
            for (int j = 0; j < 4; ++j) {
                float g = accg[i][j][r];
                float u = accu[i][j][r];
                float s = g / (1.f + __expf(-g));
                int f = f0 + wn * 64 + j * 16 + ml;
                inter[(size_t)t * F_ + f] = f2bf(cv * s * u);
            }
        }
    }
}

// GEMM 2 (down): out[t][h] += sum_f inter[t][f] * w2eT[h][f]   (NT, K=F)
// Accumulates f32 directly into d_out across the 8 expert launches.
__global__ __launch_bounds__(256) void gemm_down_kernel(
        const u16* __restrict__ inter, // [T][F] bf16
        const u16* __restrict__ bT,    // [H][F] bf16 (w2e transposed)
        float* __restrict__ outf) {    // [T][H] f32
    __shared__ __align__(16) u16 As[128 * 32];
    __shared__ __align__(16) u16 Bs[128 * 32];
    int tid = threadIdx.x;
    int lane = tid & 63, wave = tid >> 6;
    int wm = wave >> 1, wn = wave & 1;
    int t0 = blockIdx.x * 128, h0 = blockIdx.y * 128;
    int ml = lane & 15, q = lane >> 4;

    f4v acc[4][4] = {};
    const u16* ga = inter + (size_t)t0 * F_;
    const u16* gb = bT    + (size_t)h0 * F_;

    for (int k0 = 0; k0 < F_; k0 += 32) {
        __syncthreads();
#pragma unroll
        for (int p = 0; p < 2; ++p) {
            int c = p * 256 + tid;
            int r = c >> 2, co = (c & 3) * 8;
            *(int4*)(As + c * 8) = *(const int4*)(ga + (size_t)r * F_ + k0 + co);
            *(int4*)(Bs + c * 8) = *(const int4*)(gb + (size_t)r * F_ + k0 + co);
        }
        __syncthreads();
        s8v a[4], b[4];
#pragma unroll
        for (int i = 0; i < 4; ++i) {
            a[i] = *(const s8v*)(As + (wm * 64 + i * 16 + ml) * 32 + q * 8);
            b[i] = *(const s8v*)(Bs + (wn * 64 + i * 16 + ml) * 32 + q * 8);
        }
#pragma unroll
        for (int i = 0; i < 4; ++i)
#pragma unroll
            for (int j = 0; j < 4; ++j)
                acc[i][j] = __builtin_amdgcn_mfma_f32_16x16x32_bf16(a[i], b[j], acc[i][j], 0, 0, 0);
    }
#pragma unroll
    for (int i = 0; i < 4; ++i)
#pragma unroll
        for (int r = 0; r < 4; ++r) {
            int t = t0 + wm * 64 + i * 16 + q * 4 + r;
#pragma unroll
            for (int j = 0; j < 4; ++j) {
                int h = h0 + wn * 64 + j * 16 + ml;
                outf[(size_t)t * H_ + h] += acc[i][j][r];
            }
        }
}

// ---------------------------------------------------------------------------
extern "C" void kernel_launch(void* const* d_in, const int* in_sizes, int n_in,
                              void* d_out, int out_size, void* d_ws, size_t ws_size,
                              hipStream_t stream) {
    const float* x  = (const float*)d_in[0];
    // d_in[1] = router probs `weights` — unused by the reference
    const float* tw = (const float*)d_in[2];
    const int*   te = (const int*)d_in[3];
    const float* w1 = (const float*)d_in[4];
    const float* v1 = (const float*)d_in[5];
    const float* w2 = (const float*)d_in[6];
    float* out = (float*)d_out;

    // workspace (~25 MB):
    //   cw    f32 [E][T]   @ 0       (64 KB)
    //   flag  int          @ 64 KB
    //   xb    bf16 [T][H]  @ 1 MB    (4 MB)
    //   inter bf16 [T][F]  @ 5 MB    (8 MB)   reused per expert
    //   w1be  bf16 [F][H]  @ 13 MB   (4 MB)   reused per expert
    //   v1be  bf16 [F][H]  @ 17 MB   (4 MB)   reused per expert
    //   w2beT bf16 [H][F]  @ 21 MB   (4 MB)   reused per expert
    char* ws = (char*)d_ws;
    float* cw    = (float*)(ws);
    int*   flag  = (int*)(ws + (64 << 10));
    u16*   xb    = (u16*)(ws + (1 << 20));
    u16*   inter = (u16*)(ws + (5 << 20));
    u16*   w1be  = (u16*)(ws + (13 << 20));
    u16*   v1be  = (u16*)(ws + (17 << 20));
    u16*   w2beT = (u16*)(ws + (21 << 20));

    hipMemsetAsync(out, 0, (size_t)T_ * H_ * sizeof(float), stream);
    detect_kernel<<<1, 256, 0, stream>>>(te, flag);
    cw_kernel<<<T_ / 256, 256, 0, stream>>>(te, tw, flag, cw);
    cvt_kernel<<<(T_ * H_) / 1024, 256, 0, stream>>>(x, xb);

    for (int e = 0; e < E_; ++e) {
        const size_t wofs = (size_t)e * F_ * H_;
        cvt_kernel<<<(F_ * H_) / 1024, 256, 0, stream>>>(w1 + wofs, w1be);
        cvt_kernel<<<(F_ * H_) / 1024, 256, 0, stream>>>(v1 + wofs, v1be);
        tcvt_kernel<<<dim3(H_ / 64, F_ / 64), dim3(8, 32), 0, stream>>>(
            w2 + wofs, w2beT, F_, H_);
        gemm_glu_kernel<<<dim3(T_ / 128, F_ / 128), 256, 0, stream>>>(
            xb, w1be, v1be, cw + (size_t)e * T_, inter);
        gemm_down_kernel<<<dim3(T_ / 128, H_ / 128), 256, 0, stream>>>(
            inter, w2beT, out);
    }
}

// Round 3
// 507.599 us; speedup vs baseline: 1.8721x; 1.8721x over previous
//
#include <hip/hip_runtime.h>
#include <hip/hip_bf16.h>

// DBRX MoE experts forward, MI355X gfx950.
// T=2048 tokens, H=1024, F=2048, E=8, K=2. All float tensors f32 storage;
// top_experts int64 (probe handles int32 too). Output f32.
// Round 3: SPARSE routing (per-expert token lists, ~512 tok/expert), fused
// single-launch GEMMs across all experts, in-GEMM f32->bf16 weight convert,
// down-GEMM K-split with f32 atomicAdd into out. Fallback to the round-2
// dense path if ws_size < 70 MB.

#define T_ 2048
#define H_ 1024
#define F_ 2048
#define E_ 8
#define SCAP 1024        // per-expert slot capacity (mean 512, sigma 21 -> 24 sigma)
#define TPE 8            // token tiles per expert = SCAP/128

typedef unsigned short u16;
typedef short s8v __attribute__((ext_vector_type(8)));
typedef float f4v __attribute__((ext_vector_type(4)));
typedef unsigned short u16x4 __attribute__((ext_vector_type(4)));

__device__ __forceinline__ u16 f2bf(float f) {
    union { float f; unsigned u; } v; v.f = f;
    unsigned r = v.u + 0x7FFF + ((v.u >> 16) & 1);   // RNE
    return (u16)(r >> 16);
}
__device__ __forceinline__ unsigned pkbf(float a, float b) {
    __hip_bfloat162 h = __float22bfloat162_rn(make_float2(a, b));
    union { __hip_bfloat162 h; unsigned u; } c; c.h = h; return c.u;
}
__device__ __forceinline__ int4 cvt8(const float4 a, const float4 b) {
    int4 r; r.x = (int)pkbf(a.x, a.y); r.y = (int)pkbf(a.z, a.w);
    r.z = (int)pkbf(b.x, b.y); r.w = (int)pkbf(b.z, b.w); return r;
}

// ===========================================================================
// Router: build per-expert (token, weight) lists. Single block. Merges a
// token's two slots if both route to the same expert. Pads each list to a
// multiple of 128 with (tok=0, w=0) sentinels (benign zero contributions).
__global__ void router_kernel(const int* __restrict__ te, const float* __restrict__ tw,
                              int* __restrict__ cnt_g, int* __restrict__ slot_tok,
                              float* __restrict__ slot_w) {
    __shared__ int cnt[E_];
    __shared__ int s_any;
    int tid = threadIdx.x;
    if (tid < E_) cnt[tid] = 0;
    if (tid == 0) s_any = 0;
    __syncthreads();
    // int64-vs-int32 storage probe: int64 -> all odd words zero
    int any = 0;
    for (int i = tid; i < 2 * T_; i += 256) if (i & 1) any |= te[i];
    if (any) atomicOr(&s_any, 1);
    __syncthreads();
    bool is32 = (s_any != 0);
    for (int t = tid; t < T_; t += 256) {
        int e0 = is32 ? te[2 * t]     : te[4 * t];
        int e1 = is32 ? te[2 * t + 1] : te[4 * t + 2];
        float w0 = tw[2 * t], w1 = tw[2 * t + 1];
        if (e0 == e1) {
            int p = atomicAdd(&cnt[e0], 1);
            if (p < SCAP) { slot_tok[e0 * SCAP + p] = t; slot_w[e0 * SCAP + p] = w0 + w1; }
        } else {
            int p = atomicAdd(&cnt[e0], 1);
            if (p < SCAP) { slot_tok[e0 * SCAP + p] = t; slot_w[e0 * SCAP + p] = w0; }
            p = atomicAdd(&cnt[e1], 1);
            if (p < SCAP) { slot_tok[e1 * SCAP + p] = t; slot_w[e1 * SCAP + p] = w1; }
        }
    }
    __syncthreads();
    for (int e = 0; e < E_; ++e) {
        int c = min(cnt[e], SCAP);
        int pc = min((c + 127) & ~127, SCAP);
        for (int p = c + tid; p < pc; p += 256) {
            slot_tok[e * SCAP + p] = 0; slot_w[e * SCAP + p] = 0.f;
        }
    }
    if (tid < E_) cnt_g[tid] = min(cnt[tid], SCAP);
}

// f32 -> bf16 elementwise, 4/thread.
__global__ void cvt_kernel(const float* __restrict__ src, u16* __restrict__ dst) {
    int i = (blockIdx.x * 256 + threadIdx.x) * 4;
    float4 v = *(const float4*)(src + i);
    u16x4 o = { f2bf(v.x), f2bf(v.y), f2bf(v.z), f2bf(v.w) };
    *(u16x4*)(dst + i) = o;
}

// f32 [F][H] -> bf16 [H][F] per expert (blockIdx.z), 64x64 tiles.
__global__ void tcvt8_kernel(const float* __restrict__ src0, u16* __restrict__ dst0) {
    const float* src = src0 + (size_t)blockIdx.z * F_ * H_;
    u16* dst = dst0 + (size_t)blockIdx.z * H_ * F_;
    __shared__ __align__(16) u16 tile[64][72];
    int bc = blockIdx.x * 64, br = blockIdx.y * 64;
    int tx = threadIdx.x, ty = threadIdx.y;   // (8,32)
    for (int r = ty; r < 64; r += 32) {
        const float* p = src + (size_t)(br + r) * H_ + bc + tx * 8;
        float4 v0 = *(const float4*)p;
        float4 v1 = *(const float4*)(p + 4);
        u16* q = &tile[r][tx * 8];
        q[0] = f2bf(v0.x); q[1] = f2bf(v0.y); q[2] = f2bf(v0.z); q[3] = f2bf(v0.w);
        q[4] = f2bf(v1.x); q[5] = f2bf(v1.y); q[6] = f2bf(v1.z); q[7] = f2bf(v1.w);
    }
    __syncthreads();
    for (int c = ty; c < 64; c += 32) {
        u16 tmp[8];
#pragma unroll
        for (int j = 0; j < 8; ++j) tmp[j] = tile[tx * 8 + j][c];
        *(int4*)&dst[(size_t)(bc + c) * F_ + br + tx * 8] = *(int4*)tmp;
    }
}

// ===========================================================================
// Fused sparse GLU GEMM, all experts in one launch.
// block = (e, token-tile, f-tile); gathers A rows via slot_tok; converts
// w1/v1 f32->bf16 during staging. inter[slot][f] = bf16(w * silu(g) * u).
__global__ __launch_bounds__(256, 2) void glu_sparse_kernel(
        const u16* __restrict__ xb, const float* __restrict__ w1,
        const float* __restrict__ v1, const int* __restrict__ cnt_g,
        const int* __restrict__ slot_tok, const float* __restrict__ slot_w,
        u16* __restrict__ inter) {
    int e = blockIdx.x >> 3, tt = blockIdx.x & 7;
    if (tt * 128 >= cnt_g[e]) return;
    __shared__ __align__(16) u16 As[128 * 32];
    __shared__ __align__(16) u16 B1s[128 * 32];
    __shared__ __align__(16) u16 B2s[128 * 32];
    __shared__ int stok[128];
    __shared__ float sw[128];
    int tid = threadIdx.x;
    if (tid < 128) {
        stok[tid] = slot_tok[e * SCAP + tt * 128 + tid];
        sw[tid]   = slot_w[e * SCAP + tt * 128 + tid];
    }
    __syncthreads();
    int lane = tid & 63, wave = tid >> 6;
    int wm = wave >> 1, wn = wave & 1;
    int f0 = blockIdx.y * 128;
    int ml = lane & 15, q = lane >> 4;
    int r0 = tid >> 2, r1 = 64 + (tid >> 2);
    int colo = (tid & 3) * 8;
    const size_t tokoff0 = (size_t)stok[r0] * H_ + colo;
    const size_t tokoff1 = (size_t)stok[r1] * H_ + colo;
    const float* gb1 = w1 + (size_t)e * F_ * H_ + (size_t)f0 * H_;
    const float* gb2 = v1 + (size_t)e * F_ * H_ + (size_t)f0 * H_;
    const size_t boff0 = (size_t)r0 * H_ + colo;
    const size_t boff1 = (size_t)r1 * H_ + colo;

    f4v accg[4][4] = {};
    f4v accu[4][4] = {};

    for (int k0 = 0; k0 < H_; k0 += 32) {
        __syncthreads();
        *(int4*)(As + tid * 8)         = *(const int4*)(xb + tokoff0 + k0);
        *(int4*)(As + (256 + tid) * 8) = *(const int4*)(xb + tokoff1 + k0);
        {
            const float* p = gb1 + boff0 + k0;
            *(int4*)(B1s + tid * 8) = cvt8(*(const float4*)p, *(const float4*)(p + 4));
            p = gb1 + boff1 + k0;
            *(int4*)(B1s + (256 + tid) * 8) = cvt8(*(const float4*)p, *(const float4*)(p + 4));
            p = gb2 + boff0 + k0;
            *(int4*)(B2s + tid * 8) = cvt8(*(const float4*)p, *(const float4*)(p + 4));
            p = gb2 + boff1 + k0;
            *(int4*)(B2s + (256 + tid) * 8) = cvt8(*(const float4*)p, *(const float4*)(p + 4));
        }
        __syncthreads();
        s8v a[4], b1[4], b2[4];
#pragma unroll
        for (int i = 0; i < 4; ++i) {
            a[i]  = *(const s8v*)(As  + (wm * 64 + i * 16 + ml) * 32 + q * 8);
            b1[i] = *(const s8v*)(B1s + (wn * 64 + i * 16 + ml) * 32 + q * 8);
            b2[i] = *(const s8v*)(B2s + (wn * 64 + i * 16 + ml) * 32 + q * 8);
        }
#pragma unroll
        for (int i = 0; i < 4; ++i)
#pragma unroll
            for (int j = 0; j < 4; ++j) {
                accg[i][j] = __builtin_amdgcn_mfma_f32_16x16x32_bf16(a[i], b1[j], accg[i][j], 0, 0, 0);
                accu[i][j] = __builtin_amdgcn_mfma_f32_16x16x32_bf16(a[i], b2[j], accu[i][j], 0, 0, 0);
            }
    }
#pragma unroll
    for (int i = 0; i < 4; ++i) {
#pragma unroll
        for (int r = 0; r < 4; ++r) {
            int lr = wm * 64 + i * 16 + q * 4 + r;
            float cv = sw[lr];
#pragma unroll
            for (int j = 0; j < 4; ++j) {
                float g = accg[i][j][r];
                float u = accu[i][j][r];
                float s = g / (1.f + __expf(-g));
                int f = f0 + wn * 64 + j * 16 + ml;
                inter[(size_t)(e * SCAP + tt * 128 + lr) * F_ + f] = f2bf(cv * s * u);
            }
        }
    }
}

// Fused sparse down GEMM: out[tok][h] += sum_f inter[slot][f] * w2bT[e][h][f].
// K split x2 (blockIdx.z); scatter rows via f32 atomicAdd (cross-expert and
// cross-K-split accumulation).
__global__ __launch_bounds__(256) void down_sparse_kernel(
        const u16* __restrict__ inter, const u16* __restrict__ w2bT,
        const int* __restrict__ cnt_g, const int* __restrict__ slot_tok,
        float* __restrict__ out) {
    int e = blockIdx.x >> 3, tt = blockIdx.x & 7;
    if (tt * 128 >= cnt_g[e]) return;
    __shared__ __align__(16) u16 As[128 * 32];
    __shared__ __align__(16) u16 Bs[128 * 32];
    __shared__ int stok[128];
    int tid = threadIdx.x;
    if (tid < 128) stok[tid] = slot_tok[e * SCAP + tt * 128 + tid];
    __syncthreads();
    int lane = tid & 63, wave = tid >> 6;
    int wm = wave >> 1, wn = wave & 1;
    int h0 = blockIdx.y * 128;
    int ml = lane & 15, q = lane >> 4;
    int kbeg = blockIdx.z * (F_ / 2), kend = kbeg + (F_ / 2);

    f4v acc[4][4] = {};
    const u16* ga = inter + (size_t)(e * SCAP + tt * 128) * F_;
    const u16* gb = w2bT + (size_t)e * H_ * F_ + (size_t)h0 * F_;

    for (int k0 = kbeg; k0 < kend; k0 += 32) {
        __syncthreads();
#pragma unroll
        for (int p = 0; p < 2; ++p) {
            int c = p * 256 + tid;
            int r = c >> 2, co = (c & 3) * 8;
            *(int4*)(As + c * 8) = *(const int4*)(ga + (size_t)r * F_ + k0 + co);
            *(int4*)(Bs + c * 8) = *(const int4*)(gb + (size_t)r * F_ + k0 + co);
        }
        __syncthreads();
        s8v a[4], b[4];
#pragma unroll
        for (int i = 0; i < 4; ++i) {
            a[i] = *(const s8v*)(As + (wm * 64 + i * 16 + ml) * 32 + q * 8);
            b[i] = *(const s8v*)(Bs + (wn * 64 + i * 16 + ml) * 32 + q * 8);
        }
#pragma unroll
        for (int i = 0; i < 4; ++i)
#pragma unroll
            for (int j = 0; j < 4; ++j)
                acc[i][j] = __builtin_amdgcn_mfma_f32_16x16x32_bf16(a[i], b[j], acc[i][j], 0, 0, 0);
    }
#pragma unroll
    for (int i = 0; i < 4; ++i)
#pragma unroll
        for (int r = 0; r < 4; ++r) {
            int lr = wm * 64 + i * 16 + q * 4 + r;
            size_t trow = (size_t)stok[lr] * H_;
#pragma unroll
            for (int j = 0; j < 4; ++j) {
                int h = h0 + wn * 64 + j * 16 + ml;
                atomicAdd(&out[trow + h], acc[i][j][r]);
            }
        }
}

// ===========================================================================
// ============ Fallback (round-2 dense path, needs only ~25 MB) =============
__global__ void detect_kernel(const int* __restrict__ te, int* __restrict__ flag) {
    __shared__ int s;
    if (threadIdx.x == 0) s = 0;
    __syncthreads();
    int any = 0;
    for (int i = threadIdx.x; i < 2 * T_; i += 256) if (i & 1) any |= te[i];
    if (any) atomicOr(&s, 1);
    __syncthreads();
    if (threadIdx.x == 0) *flag = (s != 0) ? 1 : 0;
}
__global__ void cw_kernel(const int* __restrict__ te, const float* __restrict__ tw,
                          const int* __restrict__ flag, float* __restrict__ cw) {
    int t = blockIdx.x * 256 + threadIdx.x;
    if (t >= T_) return;
    bool is32 = (*flag != 0);
    int e0 = is32 ? te[2 * t]     : te[4 * t];
    int e1 = is32 ? te[2 * t + 1] : te[4 * t + 2];
    float w0 = tw[2 * t], w1 = tw[2 * t + 1];
#pragma unroll
    for (int e = 0; e < E_; ++e)
        cw[e * T_ + t] = (e == e0 ? w0 : 0.f) + (e == e1 ? w1 : 0.f);
}
__global__ void tcvt_kernel(const float* __restrict__ src, u16* __restrict__ dst,
                            int R, int C) {
    __shared__ __align__(16) u16 tile[64][72];
    int bc = blockIdx.x * 64, br = blockIdx.y * 64;
    int tx = threadIdx.x, ty = threadIdx.y;
    for (int r = ty; r < 64; r += 32) {
        const float* p = src + (size_t)(br + r) * C + bc + tx * 8;
        float4 v0 = *(const float4*)p;
        float4 v1 = *(const float4*)(p + 4);
        u16* q = &tile[r][tx * 8];
        q[0] = f2bf(v0.x); q[1] = f2bf(v0.y); q[2] = f2bf(v0.z); q[3] = f2bf(v0.w);
        q[4] = f2bf(v1.x); q[5] = f2bf(v1.y); q[6] = f2bf(v1.z); q[7] = f2bf(v1.w);
    }
    __syncthreads();
    for (int c = ty; c < 64; c += 32) {
        u16 tmp[8];
#pragma unroll
        for (int j = 0; j < 8; ++j) tmp[j] = tile[tx * 8 + j][c];
        *(int4*)&dst[(size_t)(bc + c) * R + br + tx * 8] = *(int4*)tmp;
    }
}
__global__ __launch_bounds__(256) void gemm_glu_kernel(
        const u16* __restrict__ xb, const u16* __restrict__ w1e,
        const u16* __restrict__ v1e, const float* __restrict__ cwe,
        u16* __restrict__ inter) {
    __shared__ __align__(16) u16 As[128 * 32];
    __shared__ __align__(16) u16 B1s[128 * 32];
    __shared__ __align__(16) u16 B2s[128 * 32];
    int tid = threadIdx.x;
    int lane = tid & 63, wave = tid >> 6;
    int wm = wave >> 1, wn = wave & 1;
    int t0 = blockIdx.x * 128, f0 = blockIdx.y * 128;
    int ml = lane & 15, q = lane >> 4;
    f4v accg[4][4] = {};
    f4v accu[4][4] = {};
    const u16* ga  = xb  + (size_t)t0 * H_;
    const u16* gb1 = w1e + (size_t)f0 * H_;
    const u16* gb2 = v1e + (size_t)f0 * H_;
    for (int k0 = 0; k0 < H_; k0 += 32) {
        __syncthreads();
#pragma unroll
        for (int p = 0; p < 2; ++p) {
            int c = p * 256 + tid;
            int r = c >> 2, co = (c & 3) * 8;
            *(int4*)(As  + c * 8) = *(const int4*)(ga  + (size_t)r * H_ + k0 + co);
            *(int4*)(B1s + c * 8) = *(const int4*)(gb1 + (size_t)r * H_ + k0 + co);
            *(int4*)(B2s + c * 8) = *(const int4*)(gb2 + (size_t)r * H_ + k0 + co);
        }
        __syncthreads();
        s8v a[4], b1[4], b2[4];
#pragma unroll
        for (int i = 0; i < 4; ++i) {
            a[i]  = *(const s8v*)(As  + (wm * 64 + i * 16 + ml) * 32 + q * 8);
            b1[i] = *(const s8v*)(B1s + (wn * 64 + i * 16 + ml) * 32 + q * 8);
            b2[i] = *(const s8v*)(B2s + (wn * 64 + i * 16 + ml) * 32 + q * 8);
        }
#pragma unroll
        for (int i = 0; i < 4; ++i)
#pragma unroll
            for (int j = 0; j < 4; ++j) {
                accg[i][j] = __builtin_amdgcn_mfma_f32_16x16x32_bf16(a[i], b1[j], accg[i][j], 0, 0, 0);
                accu[i][j] = __builtin_amdgcn_mfma_f32_16x16x32_bf16(a[i], b2[j], accu[i][j], 0, 0, 0);
            }
    }
#pragma unroll
    for (int i = 0; i < 4; ++i) {
#pragma unroll
        for (int r = 0; r < 4; ++r) {
            int t = t0 + wm * 64 + i * 16 + q * 4 + r;
            float cv = cwe[t];
#pragma unroll
            for (int j = 0; j < 4; ++j) {
                float g = accg[i][j][r];
                float u = accu[i][j][r];
                float s = g / (1.f + __expf(-g));
                int f = f0 + wn * 64 + j * 16 + ml;
                inter[(size_t)t * F_ + f] = f2bf(cv * s * u);
            }
        }
    }
}
__global__ __launch_bounds__(256) void gemm_down_kernel(
        const u16* __restrict__ inter, const u16* __restrict__ bT,
        float* __restrict__ outf) {
    __shared__ __align__(16) u16 As[128 * 32];
    __shared__ __align__(16) u16 Bs[128 * 32];
    int tid = threadIdx.x;
    int lane = tid & 63, wave = tid >> 6;
    int wm = wave >> 1, wn = wave & 1;
    int t0 = blockIdx.x * 128, h0 = blockIdx.y * 128;
    int ml = lane & 15, q = lane >> 4;
    f4v acc[4][4] = {};
    const u16* ga = inter + (size_t)t0 * F_;
    const u16* gb = bT    + (size_t)h0 * F_;
    for (int k0 = 0; k0 < F_; k0 += 32) {
        __syncthreads();
#pragma unroll
        for (int p = 0; p < 2; ++p) {
            int c = p * 256 + tid;
            int r = c >> 2, co = (c & 3) * 8;
            *(int4*)(As + c * 8) = *(const int4*)(ga + (size_t)r * F_ + k0 + co);
            *(int4*)(Bs + c * 8) = *(const int4*)(gb + (size_t)r * F_ + k0 + co);
        }
        __syncthreads();
        s8v a[4], b[4];
#pragma unroll
        for (int i = 0; i < 4; ++i) {
            a[i] = *(const s8v*)(As + (wm * 64 + i * 16 + ml) * 32 + q * 8);
            b[i] = *(const s8v*)(Bs + (wn * 64 + i * 16 + ml) * 32 + q * 8);
        }
#pragma unroll
        for (int i = 0; i < 4; ++i)
#pragma unroll
            for (int j = 0; j < 4; ++j)
                acc[i][j] = __builtin_amdgcn_mfma_f32_16x16x32_bf16(a[i], b[j], acc[i][j], 0, 0, 0);
    }
#pragma unroll
    for (int i = 0; i < 4; ++i)
#pragma unroll
        for (int r = 0; r < 4; ++r) {
            int t = t0 + wm * 64 + i * 16 + q * 4 + r;
#pragma unroll
            for (int j = 0; j < 4; ++j) {
                int h = h0 + wn * 64 + j * 16 + ml;
                outf[(size_t)t * H_ + h] += acc[i][j][r];
            }
        }
}

// ===========================================================================
extern "C" void kernel_launch(void* const* d_in, const int* in_sizes, int n_in,
                              void* d_out, int out_size, void* d_ws, size_t ws_size,
                              hipStream_t stream) {
    const float* x  = (const float*)d_in[0];
    const float* tw = (const float*)d_in[2];
    const int*   te = (const int*)d_in[3];
    const float* w1 = (const float*)d_in[4];
    const float* v1 = (const float*)d_in[5];
    const float* w2 = (const float*)d_in[6];
    float* out = (float*)d_out;
    char* ws = (char*)d_ws;

    if (ws_size >= ((size_t)70 << 20)) {
        // ---- primary sparse path (~69 MB) ----
        // cnt_g @0, slot_tok @4K (32K), slot_w @64K (32K),
        // xb @1M (4M), w2bT @5M (32M), inter @37M (32M)
        int*   cnt_g    = (int*)(ws);
        int*   slot_tok = (int*)(ws + (4 << 10));
        float* slot_w   = (float*)(ws + (64 << 10));
        u16*   xb       = (u16*)(ws + ((size_t)1 << 20));
        u16*   w2bT     = (u16*)(ws + ((size_t)5 << 20));
        u16*   inter    = (u16*)(ws + ((size_t)37 << 20));

        hipMemsetAsync(out, 0, (size_t)T_ * H_ * sizeof(float), stream);
        router_kernel<<<1, 256, 0, stream>>>(te, tw, cnt_g, slot_tok, slot_w);
        cvt_kernel<<<(T_ * H_) / 1024, 256, 0, stream>>>(x, xb);
        tcvt8_kernel<<<dim3(H_ / 64, F_ / 64, E_), dim3(8, 32), 0, stream>>>(w2, w2bT);
        glu_sparse_kernel<<<dim3(E_ * TPE, F_ / 128), 256, 0, stream>>>(
            xb, w1, v1, cnt_g, slot_tok, slot_w, inter);
        down_sparse_kernel<<<dim3(E_ * TPE, H_ / 128, 2), 256, 0, stream>>>(
            inter, w2bT, cnt_g, slot_tok, out);
    } else {
        // ---- fallback: round-2 dense path (~25 MB) ----
        float* cw    = (float*)(ws);
        int*   flag  = (int*)(ws + (64 << 10));
        u16*   xb    = (u16*)(ws + (1 << 20));
        u16*   inter = (u16*)(ws + (5 << 20));
        u16*   w1be  = (u16*)(ws + (13 << 20));
        u16*   v1be  = (u16*)(ws + (17 << 20));
        u16*   w2beT = (u16*)(ws + (21 << 20));

        hipMemsetAsync(out, 0, (size_t)T_ * H_ * sizeof(float), stream);
        detect_kernel<<<1, 256, 0, stream>>>(te, flag);
        cw_kernel<<<T_ / 256, 256, 0, stream>>>(te, tw, flag, cw);
        cvt_kernel<<<(T_ * H_) / 1024, 256, 0, stream>>>(x, xb);
        for (int e = 0; e < E_; ++e) {
            const size_t wofs = (size_t)e * F_ * H_;
            cvt_kernel<<<(F_ * H_) / 1024, 256, 0, stream>>>(w1 + wofs, w1be);
            cvt_kernel<<<(F_ * H_) / 1024, 256, 0, stream>>>(v1 + wofs, v1be);
            tcvt_kernel<<<dim3(H_ / 64, F_ / 64), dim3(8, 32), 0, stream>>>(
                w2 + wofs, w2beT, F_, H_);
            gemm_glu_kernel<<<dim3(T_ / 128, F_ / 128), 256, 0, stream>>>(
                xb, w1be, v1be, cw + (size_t)e * T_, inter);
            gemm_down_kernel<<<dim3(T_ / 128, H_ / 128), 256, 0, stream>>>(
                inter, w2beT, out);
        }
    }
}

// Round 4
// 448.939 us; speedup vs baseline: 2.1167x; 1.1307x over previous
//
#include <hip/hip_runtime.h>
#include <hip/hip_bf16.h>

// DBRX MoE experts forward, MI355X gfx950.
// T=2048, H=1024, F=2048, E=8, K=2. f32 storage in/out; bf16 MFMA compute.
// Round 4: sparse routing w/ 64-slot tiles + tile table; pre-convert weights
// to bf16 (w1,v1 elementwise; w2 transposed); pre-gather x by slot; both
// GEMMs use global_load_lds width-16 async staging (m97 structure), ~4
// blocks/CU. Fallback to proven round-3 path if ws_size < 134 MiB.

#define T_ 2048
#define H_ 1024
#define F_ 2048
#define E_ 8

#define SCAP 768        // per-expert slot capacity (mean ~480, huge margin)
#define MAXT (E_ * SCAP / 64)   // 96 max 64-slot tiles

typedef unsigned short u16;
typedef short s8v __attribute__((ext_vector_type(8)));
typedef float f4v __attribute__((ext_vector_type(4)));
typedef unsigned short u16x4 __attribute__((ext_vector_type(4)));

__device__ __forceinline__ u16 f2bf(float f) {
    union { float f; unsigned u; } v; v.f = f;
    unsigned r = v.u + 0x7FFF + ((v.u >> 16) & 1);   // RNE
    return (u16)(r >> 16);
}
__device__ __forceinline__ unsigned pkbf(float a, float b) {
    __hip_bfloat162 h = __float22bfloat162_rn(make_float2(a, b));
    union { __hip_bfloat162 h; unsigned u; } c; c.h = h; return c.u;
}
__device__ __forceinline__ int4 cvt8(const float4 a, const float4 b) {
    int4 r; r.x = (int)pkbf(a.x, a.y); r.y = (int)pkbf(a.z, a.w);
    r.z = (int)pkbf(b.x, b.y); r.w = (int)pkbf(b.z, b.w); return r;
}
// async 16B/lane global->LDS. Per-lane global gather; LDS dest is wave base +
// lane*16 (we pass per-lane ptrs consistent with that, safe either way).
__device__ __forceinline__ void async16(void* lds, const void* g) {
    __builtin_amdgcn_global_load_lds(
        (const __attribute__((address_space(1))) unsigned*)g,
        (__attribute__((address_space(3))) unsigned*)lds, 16, 0, 0);
}

// ===========================================================================
// Router: per-expert (token, weight) lists padded to x64 (tok=-1, w=0
// sentinels) + tile table (64-slot tiles, expert-sorted).
__global__ void router_kernel(const int* __restrict__ te, const float* __restrict__ tw,
                              int* __restrict__ slot_tok, float* __restrict__ slot_w,
                              int* __restrict__ tile_e, int* __restrict__ tile_s,
                              int* __restrict__ ntiles) {
    __shared__ int cnt[E_];
    __shared__ int s_any;
    int tid = threadIdx.x;
    if (tid < E_) cnt[tid] = 0;
    if (tid == 0) s_any = 0;
    __syncthreads();
    int any = 0;
    for (int i = tid; i < 2 * T_; i += 256) if (i & 1) any |= te[i];
    if (any) atomicOr(&s_any, 1);
    __syncthreads();
    bool is32 = (s_any != 0);      // int64 storage -> odd words all zero
    for (int t = tid; t < T_; t += 256) {
        int e0 = is32 ? te[2 * t]     : te[4 * t];
        int e1 = is32 ? te[2 * t + 1] : te[4 * t + 2];
        float w0 = tw[2 * t], w1 = tw[2 * t + 1];
        if (e0 == e1) {
            int p = atomicAdd(&cnt[e0], 1);
            if (p < SCAP) { slot_tok[e0 * SCAP + p] = t; slot_w[e0 * SCAP + p] = w0 + w1; }
        } else {
            int p = atomicAdd(&cnt[e0], 1);
            if (p < SCAP) { slot_tok[e0 * SCAP + p] = t; slot_w[e0 * SCAP + p] = w0; }
            p = atomicAdd(&cnt[e1], 1);
            if (p < SCAP) { slot_tok[e1 * SCAP + p] = t; slot_w[e1 * SCAP + p] = w1; }
        }
    }
    __syncthreads();
    for (int e = 0; e < E_; ++e) {
        int c = min(cnt[e], SCAP);
        int pc = min((c + 63) & ~63, SCAP);
        for (int p = c + tid; p < pc; p += 256) {
            slot_tok[e * SCAP + p] = -1; slot_w[e * SCAP + p] = 0.f;
        }
    }
    __syncthreads();
    if (tid == 0) {
        int nt = 0;
        for (int e = 0; e < E_; ++e) {
            int pc = min((min(cnt[e], SCAP) + 63) & ~63, SCAP);
            for (int s = 0; s < pc; s += 64) { tile_e[nt] = e; tile_s[nt] = e * SCAP + s; ++nt; }
        }
        *ntiles = nt;
    }
}

// f32 -> bf16 elementwise, 4/thread.
__global__ void cvt_kernel(const float* __restrict__ src, u16* __restrict__ dst) {
    int i = (blockIdx.x * 256 + threadIdx.x) * 4;
    float4 v = *(const float4*)(src + i);
    u16x4 o = { f2bf(v.x), f2bf(v.y), f2bf(v.z), f2bf(v.w) };
    *(u16x4*)(dst + i) = o;
}

// f32 [F][H] -> bf16 [H][F] per expert (blockIdx.z), 64x64 tiles.
__global__ void tcvt8_kernel(const float* __restrict__ src0, u16* __restrict__ dst0) {
    const float* src = src0 + (size_t)blockIdx.z * F_ * H_;
    u16* dst = dst0 + (size_t)blockIdx.z * H_ * F_;
    __shared__ __align__(16) u16 tile[64][72];
    int bc = blockIdx.x * 64, br = blockIdx.y * 64;
    int tx = threadIdx.x, ty = threadIdx.y;   // (8,32)
    for (int r = ty; r < 64; r += 32) {
        const float* p = src + (size_t)(br + r) * H_ + bc + tx * 8;
        float4 v0 = *(const float4*)p;
        float4 v1 = *(const float4*)(p + 4);
        u16* q = &tile[r][tx * 8];
        q[0] = f2bf(v0.x); q[1] = f2bf(v0.y); q[2] = f2bf(v0.z); q[3] = f2bf(v0.w);
        q[4] = f2bf(v1.x); q[5] = f2bf(v1.y); q[6] = f2bf(v1.z); q[7] = f2bf(v1.w);
    }
    __syncthreads();
    for (int c = ty; c < 64; c += 32) {
        u16 tmp[8];
#pragma unroll
        for (int j = 0; j < 8; ++j) tmp[j] = tile[tx * 8 + j][c];
        *(int4*)&dst[(size_t)(bc + c) * F_ + br + tx * 8] = *(int4*)tmp;
    }
}

// Gather+convert x rows into slot order: xg[slot][H] = bf16(x[tok]); zeros for
// sentinel slots. One block per tile (64 rows).
__global__ void gather_x_kernel(const float* __restrict__ x, const int* __restrict__ slot_tok,
                                const int* __restrict__ tile_s, const int* __restrict__ ntiles,
                                u16* __restrict__ xg) {
    if ((int)blockIdx.x >= *ntiles) return;
    int base = tile_s[blockIdx.x];
    int tid = threadIdx.x;
    __shared__ int stok[64];
    if (tid < 64) stok[tid] = slot_tok[base + tid];
    __syncthreads();
    for (int c = tid; c < 64 * 128; c += 256) {      // 8-elem chunks
        int r = c >> 7, co = (c & 127) * 8;
        int tok = stok[r];
        u16* dst = xg + ((size_t)(base + r) << 10) + co;
        if (tok < 0) { *(int4*)dst = make_int4(0, 0, 0, 0); }
        else {
            const float* p = x + ((size_t)tok << 10) + co;
            *(int4*)dst = cvt8(*(const float4*)p, *(const float4*)(p + 4));
        }
    }
}

// ===========================================================================
// GLU GEMM: 64(slots) x 128(f) tile, BK=32, async global->LDS staging.
// inter[slot][f] = bf16( w_slot * silu(g) * u ).
__global__ __launch_bounds__(256, 4) void glu_async_kernel(
        const u16* __restrict__ xg, const u16* __restrict__ w1b,
        const u16* __restrict__ v1b, const int* __restrict__ tile_e,
        const int* __restrict__ tile_s, const int* __restrict__ ntiles,
        const float* __restrict__ slot_w, u16* __restrict__ inter) {
    int bt = blockIdx.x;
    if (bt >= *ntiles) return;
    int e = tile_e[bt], s0 = tile_s[bt];
    int f0 = blockIdx.y * 128;
    __shared__ __align__(16) u16 As[64 * 32];
    __shared__ __align__(16) u16 B1s[128 * 32];
    __shared__ __align__(16) u16 B2s[128 * 32];
    __shared__ float swv[64];
    int tid = threadIdx.x;
    int lane = tid & 63, wave = tid >> 6;
    int wm = wave >> 1, wn = wave & 1;
    int ml = lane & 15, q = lane >> 4;
    if (tid < 64) swv[tid] = slot_w[s0 + tid];

    // staging geometry: lane l of wave w covers row base + l/4, col (l%4)*8
    int acol = (lane & 3) << 3;
    int arow = (wave << 4) + (lane >> 2);            // 0..63
    int brow0 = (wave << 5) + (lane >> 2);           // 0..127 (two issues)
    int brow1 = brow0 + 16;
    const u16* gA  = xg + ((size_t)(s0 + arow) << 10) + acol;
    const size_t wofs = (size_t)e * F_ * H_;
    const u16* gB10 = w1b + wofs + ((size_t)(f0 + brow0) << 10) + acol;
    const u16* gB11 = w1b + wofs + ((size_t)(f0 + brow1) << 10) + acol;
    const u16* gB20 = v1b + wofs + ((size_t)(f0 + brow0) << 10) + acol;
    const u16* gB21 = v1b + wofs + ((size_t)(f0 + brow1) << 10) + acol;
    u16* lA  = As  + (arow  << 5) + acol;
    u16* lB10 = B1s + (brow0 << 5) + acol;
    u16* lB11 = B1s + (brow1 << 5) + acol;
    u16* lB20 = B2s + (brow0 << 5) + acol;
    u16* lB21 = B2s + (brow1 << 5) + acol;

    f4v accg[2][4] = {};
    f4v accu[2][4] = {};

    for (int k0 = 0; k0 < H_; k0 += 32) {
        __syncthreads();
        async16(lA,  gA  + k0);
        async16(lB10, gB10 + k0);
        async16(lB11, gB11 + k0);
        async16(lB20, gB20 + k0);
        async16(lB21, gB21 + k0);
        __syncthreads();
        s8v a[2], b1[4], b2[4];
#pragma unroll
        for (int i = 0; i < 2; ++i)
            a[i] = *(const s8v*)(As + (wm * 32 + i * 16 + ml) * 32 + q * 8);
#pragma unroll
        for (int j = 0; j < 4; ++j) {
            b1[j] = *(const s8v*)(B1s + (wn * 64 + j * 16 + ml) * 32 + q * 8);
            b2[j] = *(const s8v*)(B2s + (wn * 64 + j * 16 + ml) * 32 + q * 8);
        }
#pragma unroll
        for (int i = 0; i < 2; ++i)
#pragma unroll
            for (int j = 0; j < 4; ++j) {
                accg[i][j] = __builtin_amdgcn_mfma_f32_16x16x32_bf16(a[i], b1[j], accg[i][j], 0, 0, 0);
                accu[i][j] = __builtin_amdgcn_mfma_f32_16x16x32_bf16(a[i], b2[j], accu[i][j], 0, 0, 0);
            }
    }
#pragma unroll
    for (int i = 0; i < 2; ++i)
#pragma unroll
        for (int r = 0; r < 4; ++r) {
            int lr = wm * 32 + i * 16 + q * 4 + r;
            float cv = swv[lr];
#pragma unroll
            for (int j = 0; j < 4; ++j) {
                float g = accg[i][j][r];
                float u = accu[i][j][r];
                float s = g / (1.f + __expf(-g));
                int f = f0 + wn * 64 + j * 16 + ml;
                inter[((size_t)(s0 + lr) << 11) + f] = f2bf(cv * s * u);
            }
        }
}

// Down GEMM: 64(slots) x 128(h), K=F split x2, async staging, scatter rows to
// out via f32 atomicAdd. Sentinel rows (tok<0) skipped.
__global__ __launch_bounds__(256, 4) void down_async_kernel(
        const u16* __restrict__ inter, const u16* __restrict__ w2bT,
        const int* __restrict__ tile_e, const int* __restrict__ tile_s,
        const int* __restrict__ ntiles, const int* __restrict__ slot_tok,
        float* __restrict__ out) {
    int bt = blockIdx.x;
    if (bt >= *ntiles) return;
    int e = tile_e[bt], s0 = tile_s[bt];
    int h0 = blockIdx.y * 128;
    int kbeg = blockIdx.z * (F_ / 2);
    __shared__ __align__(16) u16 As[64 * 32];
    __shared__ __align__(16) u16 Bs[128 * 32];
    __shared__ int stok[64];
    int tid = threadIdx.x;
    int lane = tid & 63, wave = tid >> 6;
    int wm = wave >> 1, wn = wave & 1;
    int ml = lane & 15, q = lane >> 4;
    if (tid < 64) stok[tid] = slot_tok[s0 + tid];

    int acol = (lane & 3) << 3;
    int arow = (wave << 4) + (lane >> 2);
    int brow0 = (wave << 5) + (lane >> 2);
    int brow1 = brow0 + 16;
    const u16* gA  = inter + ((size_t)(s0 + arow) << 11) + kbeg + acol;
    const u16* gB0 = w2bT + (size_t)e * H_ * F_ + ((size_t)(h0 + brow0) << 11) + kbeg + acol;
    const u16* gB1 = w2bT + (size_t)e * H_ * F_ + ((size_t)(h0 + brow1) << 11) + kbeg + acol;
    u16* lA  = As + (arow  << 5) + acol;
    u16* lB0 = Bs + (brow0 << 5) + acol;
    u16* lB1 = Bs + (brow1 << 5) + acol;

    f4v acc[2][4] = {};
    for (int k0 = 0; k0 < F_ / 2; k0 += 32) {
        __syncthreads();
        async16(lA,  gA  + k0);
        async16(lB0, gB0 + k0);
        async16(lB1, gB1 + k0);
        __syncthreads();
        s8v a[2], b[4];
#pragma unroll
        for (int i = 0; i < 2; ++i)
            a[i] = *(const s8v*)(As + (wm * 32 + i * 16 + ml) * 32 + q * 8);
#pragma unroll
        for (int j = 0; j < 4; ++j)
            b[j] = *(const s8v*)(Bs + (wn * 64 + j * 16 + ml) * 32 + q * 8);
#pragma unroll
        for (int i = 0; i < 2; ++i)
#pragma unroll
            for (int j = 0; j < 4; ++j)
                acc[i][j] = __builtin_amdgcn_mfma_f32_16x16x32_bf16(a[i], b[j], acc[i][j], 0, 0, 0);
    }
#pragma unroll
    for (int i = 0; i < 2; ++i)
#pragma unroll
        for (int r = 0; r < 4; ++r) {
            int lr = wm * 32 + i * 16 + q * 4 + r;
            int tok = stok[lr];
            if (tok < 0) continue;
            size_t trow = (size_t)tok << 10;
#pragma unroll
            for (int j = 0; j < 4; ++j) {
                int h = h0 + wn * 64 + j * 16 + ml;
                atomicAdd(&out[trow + h], acc[i][j][r]);
            }
        }
}

// ===========================================================================
// ================= Fallback: proven round-3 path (~69 MB) ==================
#define SCAP3 1024
__global__ void router3_kernel(const int* __restrict__ te, const float* __restrict__ tw,
                               int* __restrict__ cnt_g, int* __restrict__ slot_tok,
                               float* __restrict__ slot_w) {
    __shared__ int cnt[E_];
    __shared__ int s_any;
    int tid = threadIdx.x;
    if (tid < E_) cnt[tid] = 0;
    if (tid == 0) s_any = 0;
    __syncthreads();
    int any = 0;
    for (int i = tid; i < 2 * T_; i += 256) if (i & 1) any |= te[i];
    if (any) atomicOr(&s_any, 1);
    __syncthreads();
    bool is32 = (s_any != 0);
    for (int t = tid; t < T_; t += 256) {
        int e0 = is32 ? te[2 * t]     : te[4 * t];
        int e1 = is32 ? te[2 * t + 1] : te[4 * t + 2];
        float w0 = tw[2 * t], w1 = tw[2 * t + 1];
        if (e0 == e1) {
            int p = atomicAdd(&cnt[e0], 1);
            if (p < SCAP3) { slot_tok[e0 * SCAP3 + p] = t; slot_w[e0 * SCAP3 + p] = w0 + w1; }
        } else {
            int p = atomicAdd(&cnt[e0], 1);
            if (p < SCAP3) { slot_tok[e0 * SCAP3 + p] = t; slot_w[e0 * SCAP3 + p] = w0; }
            p = atomicAdd(&cnt[e1], 1);
            if (p < SCAP3) { slot_tok[e1 * SCAP3 + p] = t; slot_w[e1 * SCAP3 + p] = w1; }
        }
    }
    __syncthreads();
    for (int e = 0; e < E_; ++e) {
        int c = min(cnt[e], SCAP3);
        int pc = min((c + 127) & ~127, SCAP3);
        for (int p = c + tid; p < pc; p += 256) {
            slot_tok[e * SCAP3 + p] = 0; slot_w[e * SCAP3 + p] = 0.f;
        }
    }
    if (tid < E_) cnt_g[tid] = min(cnt[tid], SCAP3);
}
__global__ __launch_bounds__(256, 2) void glu3_kernel(
        const u16* __restrict__ xb, const float* __restrict__ w1,
        const float* __restrict__ v1, const int* __restrict__ cnt_g,
        const int* __restrict__ slot_tok, const float* __restrict__ slot_w,
        u16* __restrict__ inter) {
    int e = blockIdx.x >> 3, tt = blockIdx.x & 7;
    if (tt * 128 >= cnt_g[e]) return;
    __shared__ __align__(16) u16 As[128 * 32];
    __shared__ __align__(16) u16 B1s[128 * 32];
    __shared__ __align__(16) u16 B2s[128 * 32];
    __shared__ int stok[128];
    __shared__ float sw[128];
    int tid = threadIdx.x;
    if (tid < 128) {
        stok[tid] = slot_tok[e * SCAP3 + tt * 128 + tid];
        sw[tid]   = slot_w[e * SCAP3 + tt * 128 + tid];
    }
    __syncthreads();
    int lane = tid & 63, wave = tid >> 6;
    int wm = wave >> 1, wn = wave & 1;
    int f0 = blockIdx.y * 128;
    int ml = lane & 15, q = lane >> 4;
    int r0 = tid >> 2, r1 = 64 + (tid >> 2);
    int colo = (tid & 3) * 8;
    const size_t tokoff0 = (size_t)stok[r0] * H_ + colo;
    const size_t tokoff1 = (size_t)stok[r1] * H_ + colo;
    const float* gb1 = w1 + (size_t)e * F_ * H_ + (size_t)f0 * H_;
    const float* gb2 = v1 + (size_t)e * F_ * H_ + (size_t)f0 * H_;
    const size_t boff0 = (size_t)r0 * H_ + colo;
    const size_t boff1 = (size_t)r1 * H_ + colo;
    f4v accg[4][4] = {};
    f4v accu[4][4] = {};
    for (int k0 = 0; k0 < H_; k0 += 32) {
        __syncthreads();
        *(int4*)(As + tid * 8)         = *(const int4*)(xb + tokoff0 + k0);
        *(int4*)(As + (256 + tid) * 8) = *(const int4*)(xb + tokoff1 + k0);
        const float* p = gb1 + boff0 + k0;
        *(int4*)(B1s + tid * 8) = cvt8(*(const float4*)p, *(const float4*)(p + 4));
        p = gb1 + boff1 + k0;
        *(int4*)(B1s + (256 + tid) * 8) = cvt8(*(const float4*)p, *(const float4*)(p + 4));
        p = gb2 + boff0 + k0;
        *(int4*)(B2s + tid * 8) = cvt8(*(const float4*)p, *(const float4*)(p + 4));
        p = gb2 + boff1 + k0;
        *(int4*)(B2s + (256 + tid) * 8) = cvt8(*(const float4*)p, *(const float4*)(p + 4));
        __syncthreads();
        s8v a[4], b1[4], b2[4];
#pragma unroll
        for (int i = 0; i < 4; ++i) {
            a[i]  = *(const s8v*)(As  + (wm * 64 + i * 16 + ml) * 32 + q * 8);
            b1[i] = *(const s8v*)(B1s + (wn * 64 + i * 16 + ml) * 32 + q * 8);
            b2[i] = *(const s8v*)(B2s + (wn * 64 + i * 16 + ml) * 32 + q * 8);
        }
#pragma unroll
        for (int i = 0; i < 4; ++i)
#pragma unroll
            for (int j = 0; j < 4; ++j) {
                accg[i][j] = __builtin_amdgcn_mfma_f32_16x16x32_bf16(a[i], b1[j], accg[i][j], 0, 0, 0);
                accu[i][j] = __builtin_amdgcn_mfma_f32_16x16x32_bf16(a[i], b2[j], accu[i][j], 0, 0, 0);
            }
    }
#pragma unroll
    for (int i = 0; i < 4; ++i)
#pragma unroll
        for (int r = 0; r < 4; ++r) {
            int lr = wm * 64 + i * 16 + q * 4 + r;
            float cv = sw[lr];
#pragma unroll
            for (int j = 0; j < 4; ++j) {
                float g = accg[i][j][r];
                float u = accu[i][j][r];
                float s = g / (1.f + __expf(-g));
                int f = f0 + wn * 64 + j * 16 + ml;
                inter[(size_t)(e * SCAP3 + tt * 128 + lr) * F_ + f] = f2bf(cv * s * u);
            }
        }
}
__global__ __launch_bounds__(256) void down3_kernel(
        const u16* __restrict__ inter, const u16* __restrict__ w2bT,
        const int* __restrict__ cnt_g, const int* __restrict__ slot_tok,
        float* __restrict__ out) {
    int e = blockIdx.x >> 3, tt = blockIdx.x & 7;
    if (tt * 128 >= cnt_g[e]) return;
    __shared__ __align__(16) u16 As[128 * 32];
    __shared__ __align__(16) u16 Bs[128 * 32];
    __shared__ int stok[128];
    int tid = threadIdx.x;
    if (tid < 128) stok[tid] = slot_tok[e * SCAP3 + tt * 128 + tid];
    __syncthreads();
    int lane = tid & 63, wave = tid >> 6;
    int wm = wave >> 1, wn = wave & 1;
    int h0 = blockIdx.y * 128;
    int ml = lane & 15, q = lane >> 4;
    int kbeg = blockIdx.z * (F_ / 2), kend = kbeg + (F_ / 2);
    f4v acc[4][4] = {};
    const u16* ga = inter + (size_t)(e * SCAP3 + tt * 128) * F_;
    const u16* gb = w2bT + (size_t)e * H_ * F_ + (size_t)h0 * F_;
    for (int k0 = kbeg; k0 < kend; k0 += 32) {
        __syncthreads();
#pragma unroll
        for (int p = 0; p < 2; ++p) {
            int c = p * 256 + tid;
            int r = c >> 2, co = (c & 3) * 8;
            *(int4*)(As + c * 8) = *(const int4*)(ga + (size_t)r * F_ + k0 + co);
            *(int4*)(Bs + c * 8) = *(const int4*)(gb + (size_t)r * F_ + k0 + co);
        }
        __syncthreads();
        s8v a[4], b[4];
#pragma unroll
        for (int i = 0; i < 4; ++i) {
            a[i] = *(const s8v*)(As + (wm * 64 + i * 16 + ml) * 32 + q * 8);
            b[i] = *(const s8v*)(Bs + (wn * 64 + i * 16 + ml) * 32 + q * 8);
        }
#pragma unroll
        for (int i = 0; i < 4; ++i)
#pragma unroll
            for (int j = 0; j < 4; ++j)
                acc[i][j] = __builtin_amdgcn_mfma_f32_16x16x32_bf16(a[i], b[j], acc[i][j], 0, 0, 0);
    }
#pragma unroll
    for (int i = 0; i < 4; ++i)
#pragma unroll
        for (int r = 0; r < 4; ++r) {
            int lr = wm * 64 + i * 16 + q * 4 + r;
            size_t trow = (size_t)stok[lr] * H_;
#pragma unroll
            for (int j = 0; j < 4; ++j) {
                int h = h0 + wn * 64 + j * 16 + ml;
                atomicAdd(&out[trow + h], acc[i][j][r]);
            }
        }
}

// ===========================================================================
extern "C" void kernel_launch(void* const* d_in, const int* in_sizes, int n_in,
                              void* d_out, int out_size, void* d_ws, size_t ws_size,
                              hipStream_t stream) {
    const float* x  = (const float*)d_in[0];
    const float* tw = (const float*)d_in[2];
    const int*   te = (const int*)d_in[3];
    const float* w1 = (const float*)d_in[4];
    const float* v1 = (const float*)d_in[5];
    const float* w2 = (const float*)d_in[6];
    float* out = (float*)d_out;
    char* ws = (char*)d_ws;

    if (ws_size >= ((size_t)135 << 20)) {
        // ---- primary async path (~133 MiB) ----
        // meta @0 (64K): slot_tok @4K (24K), slot_w @32K (24K), tile_e @1K,
        //   tile_s @2K, ntiles @256
        // xg @1M (12M) | w1b @13M (32M) | v1b @45M (32M) | w2bT @77M (32M)
        // inter @109M (24M)
        int*   tile_e   = (int*)(ws + (1 << 10));
        int*   tile_s   = (int*)(ws + (2 << 10));
        int*   ntiles   = (int*)(ws + 256);
        int*   slot_tok = (int*)(ws + (4 << 10));
        float* slot_w   = (float*)(ws + (32 << 10));
        u16*   xg       = (u16*)(ws + ((size_t)1 << 20));
        u16*   w1b      = (u16*)(ws + ((size_t)13 << 20));
        u16*   v1b      = (u16*)(ws + ((size_t)45 << 20));
        u16*   w2bT     = (u16*)(ws + ((size_t)77 << 20));
        u16*   inter    = (u16*)(ws + ((size_t)109 << 20));

        hipMemsetAsync(out, 0, (size_t)T_ * H_ * sizeof(float), stream);
        router_kernel<<<1, 256, 0, stream>>>(te, tw, slot_tok, slot_w, tile_e, tile_s, ntiles);
        cvt_kernel<<<(E_ * F_ * H_) / 1024, 256, 0, stream>>>(w1, w1b);
        cvt_kernel<<<(E_ * F_ * H_) / 1024, 256, 0, stream>>>(v1, v1b);
        tcvt8_kernel<<<dim3(H_ / 64, F_ / 64, E_), dim3(8, 32), 0, stream>>>(w2, w2bT);
        gather_x_kernel<<<MAXT, 256, 0, stream>>>(x, slot_tok, tile_s, ntiles, xg);
        glu_async_kernel<<<dim3(MAXT, F_ / 128), 256, 0, stream>>>(
            xg, w1b, v1b, tile_e, tile_s, ntiles, slot_w, inter);
        down_async_kernel<<<dim3(MAXT, H_ / 128, 2), 256, 0, stream>>>(
            inter, w2bT, tile_e, tile_s, ntiles, slot_tok, out);
    } else {
        // ---- fallback: round-3 path (~69 MB, proven) ----
        int*   cnt_g    = (int*)(ws);
        int*   slot_tok = (int*)(ws + (4 << 10));
        float* slot_w   = (float*)(ws + (64 << 10));
        u16*   xb       = (u16*)(ws + ((size_t)1 << 20));
        u16*   w2bT     = (u16*)(ws + ((size_t)5 << 20));
        u16*   inter    = (u16*)(ws + ((size_t)37 << 20));

        hipMemsetAsync(out, 0, (size_t)T_ * H_ * sizeof(float), stream);
        router3_kernel<<<1, 256, 0, stream>>>(te, tw, cnt_g, slot_tok, slot_w);
        cvt_kernel<<<(T_ * H_) / 1024, 256, 0, stream>>>(x, xb);
        tcvt8_kernel<<<dim3(H_ / 64, F_ / 64, E_), dim3(8, 32), 0, stream>>>(w2, w2bT);
        glu3_kernel<<<dim3(E_ * 8, F_ / 128), 256, 0, stream>>>(
            xb, w1, v1, cnt_g, slot_tok, slot_w, inter);
        down3_kernel<<<dim3(E_ * 8, H_ / 128, 2), 256, 0, stream>>>(
            inter, w2bT, cnt_g, slot_tok, out);
    }
}

// Round 5
// 374.312 us; speedup vs baseline: 2.5387x; 1.1994x over previous
//
#include <hip/hip_runtime.h>
#include <hip/hip_bf16.h>

// DBRX MoE experts forward, MI355X gfx950.
// T=2048, H=1024, F=2048, E=8, K=2. f32 storage in/out; bf16 MFMA compute.
// Round 5: M=128 token tiles (halve weight re-reads vs r4), XCD-aware grid
// order (same-(e,f0) blocks spaced 16 apart -> same XCD -> L2 weight reuse),
// async global_load_lds staging, pre-converted bf16 weights.
// Fallback to proven round-3 path if ws_size < 135 MiB.

#define T_ 2048
#define H_ 1024
#define F_ 2048
#define E_ 8

#define SCAP 768                  // per-expert slot capacity (multiple of 128)
#define MAXT2 (E_ * SCAP / 128)   // 48 max 128-slot tiles

typedef unsigned short u16;
typedef short s8v __attribute__((ext_vector_type(8)));
typedef float f4v __attribute__((ext_vector_type(4)));
typedef unsigned short u16x4 __attribute__((ext_vector_type(4)));

__device__ __forceinline__ u16 f2bf(float f) {
    union { float f; unsigned u; } v; v.f = f;
    unsigned r = v.u + 0x7FFF + ((v.u >> 16) & 1);   // RNE
    return (u16)(r >> 16);
}
__device__ __forceinline__ unsigned pkbf(float a, float b) {
    __hip_bfloat162 h = __float22bfloat162_rn(make_float2(a, b));
    union { __hip_bfloat162 h; unsigned u; } c; c.h = h; return c.u;
}
__device__ __forceinline__ int4 cvt8(const float4 a, const float4 b) {
    int4 r; r.x = (int)pkbf(a.x, a.y); r.y = (int)pkbf(a.z, a.w);
    r.z = (int)pkbf(b.x, b.y); r.w = (int)pkbf(b.z, b.w); return r;
}
// async 16B/lane global->LDS. LDS side resolves to wave-base + lane*16; our
// staging geometry keeps per-lane LDS addr == base + lane*16 (row=wb+lane/4,
// col=(lane&3)*8 over 64B rows).
__device__ __forceinline__ void async16(void* lds, const void* g) {
    __builtin_amdgcn_global_load_lds(
        (const __attribute__((address_space(1))) unsigned*)g,
        (__attribute__((address_space(3))) unsigned*)lds, 16, 0, 0);
}

// ===========================================================================
// Router: per-expert (token, weight) lists padded to x128 (tok=-1, w=0) +
// tile table of 128-slot tiles (expert-sorted).
__global__ void router_kernel(const int* __restrict__ te, const float* __restrict__ tw,
                              int* __restrict__ slot_tok, float* __restrict__ slot_w,
                              int* __restrict__ tile_e, int* __restrict__ tile_s,
                              int* __restrict__ ntiles) {
    __shared__ int cnt[E_];
    __shared__ int s_any;
    int tid = threadIdx.x;
    if (tid < E_) cnt[tid] = 0;
    if (tid == 0) s_any = 0;
    __syncthreads();
    int any = 0;
    for (int i = tid; i < 2 * T_; i += 256) if (i & 1) any |= te[i];
    if (any) atomicOr(&s_any, 1);
    __syncthreads();
    bool is32 = (s_any != 0);      // int64 storage -> odd words all zero
    for (int t = tid; t < T_; t += 256) {
        int e0 = is32 ? te[2 * t]     : te[4 * t];
        int e1 = is32 ? te[2 * t + 1] : te[4 * t + 2];
        float w0 = tw[2 * t], w1 = tw[2 * t + 1];
        if (e0 == e1) {
            int p = atomicAdd(&cnt[e0], 1);
            if (p < SCAP) { slot_tok[e0 * SCAP + p] = t; slot_w[e0 * SCAP + p] = w0 + w1; }
        } else {
            int p = atomicAdd(&cnt[e0], 1);
            if (p < SCAP) { slot_tok[e0 * SCAP + p] = t; slot_w[e0 * SCAP + p] = w0; }
            p = atomicAdd(&cnt[e1], 1);
            if (p < SCAP) { slot_tok[e1 * SCAP + p] = t; slot_w[e1 * SCAP + p] = w1; }
        }
    }
    __syncthreads();
    for (int e = 0; e < E_; ++e) {
        int c = min(cnt[e], SCAP);
        int pc = min((c + 127) & ~127, SCAP);
        for (int p = c + tid; p < pc; p += 256) {
            slot_tok[e * SCAP + p] = -1; slot_w[e * SCAP + p] = 0.f;
        }
    }
    __syncthreads();
    if (tid == 0) {
        int nt = 0;
        for (int e = 0; e < E_; ++e) {
            int pc = min((min(cnt[e], SCAP) + 127) & ~127, SCAP);
            for (int s = 0; s < pc; s += 128) { tile_e[nt] = e; tile_s[nt] = e * SCAP + s; ++nt; }
        }
        *ntiles = nt;
    }
}

// f32 -> bf16 elementwise, 4/thread.
__global__ void cvt_kernel(const float* __restrict__ src, u16* __restrict__ dst) {
    int i = (blockIdx.x * 256 + threadIdx.x) * 4;
    float4 v = *(const float4*)(src + i);
    u16x4 o = { f2bf(v.x), f2bf(v.y), f2bf(v.z), f2bf(v.w) };
    *(u16x4*)(dst + i) = o;
}

// f32 [F][H] -> bf16 [H][F] per expert (blockIdx.z), 64x64 tiles.
__global__ void tcvt8_kernel(const float* __restrict__ src0, u16* __restrict__ dst0) {
    const float* src = src0 + (size_t)blockIdx.z * F_ * H_;
    u16* dst = dst0 + (size_t)blockIdx.z * H_ * F_;
    __shared__ __align__(16) u16 tile[64][72];
    int bc = blockIdx.x * 64, br = blockIdx.y * 64;
    int tx = threadIdx.x, ty = threadIdx.y;   // (8,32)
    for (int r = ty; r < 64; r += 32) {
        const float* p = src + (size_t)(br + r) * H_ + bc + tx * 8;
        float4 v0 = *(const float4*)p;
        float4 v1 = *(const float4*)(p + 4);
        u16* q = &tile[r][tx * 8];
        q[0] = f2bf(v0.x); q[1] = f2bf(v0.y); q[2] = f2bf(v0.z); q[3] = f2bf(v0.w);
        q[4] = f2bf(v1.x); q[5] = f2bf(v1.y); q[6] = f2bf(v1.z); q[7] = f2bf(v1.w);
    }
    __syncthreads();
    for (int c = ty; c < 64; c += 32) {
        u16 tmp[8];
#pragma unroll
        for (int j = 0; j < 8; ++j) tmp[j] = tile[tx * 8 + j][c];
        *(int4*)&dst[(size_t)(bc + c) * F_ + br + tx * 8] = *(int4*)tmp;
    }
}

// Gather+convert x rows into slot order: xg[slot][H] = bf16(x[tok]); zeros
// for sentinels. One block per 128-slot tile.
__global__ void gather_x_kernel(const float* __restrict__ x, const int* __restrict__ slot_tok,
                                const int* __restrict__ tile_s, const int* __restrict__ ntiles,
                                u16* __restrict__ xg) {
    if ((int)blockIdx.x >= *ntiles) return;
    int base = tile_s[blockIdx.x];
    int tid = threadIdx.x;
    __shared__ int stok[128];
    if (tid < 128) stok[tid] = slot_tok[base + tid];
    __syncthreads();
    for (int c = tid; c < 128 * 128; c += 256) {      // 8-elem chunks
        int r = c >> 7, co = (c & 127) * 8;
        int tok = stok[r];
        u16* dst = xg + ((size_t)(base + r) << 10) + co;
        if (tok < 0) { *(int4*)dst = make_int4(0, 0, 0, 0); }
        else {
            const float* p = x + ((size_t)tok << 10) + co;
            *(int4*)dst = cvt8(*(const float4*)p, *(const float4*)(p + 4));
        }
    }
}

// ===========================================================================
// GLU GEMM: 128(slots) x 128(f), BK=32, async staging, dual acc.
// grid = (f-tile 16, token-tile 48): same-(e,f0) blocks spaced 16 apart in
// linear id -> same XCD (id%8) -> weight tiles served from L2 after 1st read.
__global__ __launch_bounds__(256, 2) void glu_async_kernel(
        const u16* __restrict__ xg, const u16* __restrict__ w1b,
        const u16* __restrict__ v1b, const int* __restrict__ tile_e,
        const int* __restrict__ tile_s, const int* __restrict__ ntiles,
        const float* __restrict__ slot_w, u16* __restrict__ inter) {
    int bt = blockIdx.y;
    if (bt >= *ntiles) return;
    int e = tile_e[bt], s0 = tile_s[bt];
    int f0 = blockIdx.x * 128;
    __shared__ __align__(16) u16 As[128 * 32];
    __shared__ __align__(16) u16 B1s[128 * 32];
    __shared__ __align__(16) u16 B2s[128 * 32];
    __shared__ float swv[128];
    int tid = threadIdx.x;
    int lane = tid & 63, wave = tid >> 6;
    int wm = wave >> 1, wn = wave & 1;
    int ml = lane & 15, q = lane >> 4;
    if (tid < 128) swv[tid] = slot_w[s0 + tid];

    // staging geometry: per issue, wave w covers rows w*16 + lane/4 (+row offset),
    // col (lane%4)*8 -> LDS addr = base + lane*16 (async16 invariant).
    int acol = (lane & 3) << 3;
    int row0 = (wave << 4) + (lane >> 2);            // 0..63
    int row1 = row0 + 64;
    const u16* gA0  = xg + ((size_t)(s0 + row0) << 10) + acol;
    const u16* gA1  = xg + ((size_t)(s0 + row1) << 10) + acol;
    const size_t wofs = (size_t)e * F_ * H_;
    const u16* gB10 = w1b + wofs + ((size_t)(f0 + row0) << 10) + acol;
    const u16* gB11 = w1b + wofs + ((size_t)(f0 + row1) << 10) + acol;
    const u16* gB20 = v1b + wofs + ((size_t)(f0 + row0) << 10) + acol;
    const u16* gB21 = v1b + wofs + ((size_t)(f0 + row1) << 10) + acol;
    u16* lA0  = As  + (row0 << 5) + acol;
    u16* lA1  = As  + (row1 << 5) + acol;
    u16* lB10 = B1s + (row0 << 5) + acol;
    u16* lB11 = B1s + (row1 << 5) + acol;
    u16* lB20 = B2s + (row0 << 5) + acol;
    u16* lB21 = B2s + (row1 << 5) + acol;

    f4v accg[4][4] = {};
    f4v accu[4][4] = {};

    for (int k0 = 0; k0 < H_; k0 += 32) {
        __syncthreads();
        async16(lA0,  gA0  + k0);
        async16(lA1,  gA1  + k0);
        async16(lB10, gB10 + k0);
        async16(lB11, gB11 + k0);
        async16(lB20, gB20 + k0);
        async16(lB21, gB21 + k0);
        __syncthreads();
        s8v a[4], b1[4], b2[4];
#pragma unroll
        for (int i = 0; i < 4; ++i) {
            a[i]  = *(const s8v*)(As  + (wm * 64 + i * 16 + ml) * 32 + q * 8);
            b1[i] = *(const s8v*)(B1s + (wn * 64 + i * 16 + ml) * 32 + q * 8);
            b2[i] = *(const s8v*)(B2s + (wn * 64 + i * 16 + ml) * 32 + q * 8);
        }
#pragma unroll
        for (int i = 0; i < 4; ++i)
#pragma unroll
            for (int j = 0; j < 4; ++j) {
                accg[i][j] = __builtin_amdgcn_mfma_f32_16x16x32_bf16(a[i], b1[j], accg[i][j], 0, 0, 0);
                accu[i][j] = __builtin_amdgcn_mfma_f32_16x16x32_bf16(a[i], b2[j], accu[i][j], 0, 0, 0);
            }
    }
#pragma unroll
    for (int i = 0; i < 4; ++i)
#pragma unroll
        for (int r = 0; r < 4; ++r) {
            int lr = wm * 64 + i * 16 + q * 4 + r;
            float cv = swv[lr];
#pragma unroll
            for (int j = 0; j < 4; ++j) {
                float g = accg[i][j][r];
                float u = accu[i][j][r];
                float s = g / (1.f + __expf(-g));
                int f = f0 + wn * 64 + j * 16 + ml;
                inter[((size_t)(s0 + lr) << 11) + f] = f2bf(cv * s * u);
            }
        }
}

// Down GEMM: 128(slots) x 128(h), K=F split x2, async staging, atomic scatter.
// grid = (h-tile 8, token-tile 48, ksplit 2): same-(e,h0) blocks spaced 8 ->
// same XCD -> w2bT L2 reuse.
__global__ __launch_bounds__(256, 2) void down_async_kernel(
        const u16* __restrict__ inter, const u16* __restrict__ w2bT,
        const int* __restrict__ tile_e, const int* __restrict__ tile_s,
        const int* __restrict__ ntiles, const int* __restrict__ slot_tok,
        float* __restrict__ out) {
    int bt = blockIdx.y;
    if (bt >= *ntiles) return;
    int e = tile_e[bt], s0 = tile_s[bt];
    int h0 = blockIdx.x * 128;
    int kbeg = blockIdx.z * (F_ / 2);
    __shared__ __align__(16) u16 As[128 * 32];
    __shared__ __align__(16) u16 Bs[128 * 32];
    __shared__ int stok[128];
    int tid = threadIdx.x;
    int lane = tid & 63, wave = tid >> 6;
    int wm = wave >> 1, wn = wave & 1;
    int ml = lane & 15, q = lane >> 4;
    if (tid < 128) stok[tid] = slot_tok[s0 + tid];

    int acol = (lane & 3) << 3;
    int row0 = (wave << 4) + (lane >> 2);
    int row1 = row0 + 64;
    const u16* gA0 = inter + ((size_t)(s0 + row0) << 11) + kbeg + acol;
    const u16* gA1 = inter + ((size_t)(s0 + row1) << 11) + kbeg + acol;
    const u16* gB0 = w2bT + (size_t)e * H_ * F_ + ((size_t)(h0 + row0) << 11) + kbeg + acol;
    const u16* gB1 = w2bT + (size_t)e * H_ * F_ + ((size_t)(h0 + row1) << 11) + kbeg + acol;
    u16* lA0 = As + (row0 << 5) + acol;
    u16* lA1 = As + (row1 << 5) + acol;
    u16* lB0 = Bs + (row0 << 5) + acol;
    u16* lB1 = Bs + (row1 << 5) + acol;

    f4v acc[4][4] = {};
    for (int k0 = 0; k0 < F_ / 2; k0 += 32) {
        __syncthreads();
        async16(lA0, gA0 + k0);
        async16(lA1, gA1 + k0);
        async16(lB0, gB0 + k0);
        async16(lB1, gB1 + k0);
        __syncthreads();
        s8v a[4], b[4];
#pragma unroll
        for (int i = 0; i < 4; ++i) {
            a[i] = *(const s8v*)(As + (wm * 64 + i * 16 + ml) * 32 + q * 8);
            b[i] = *(const s8v*)(Bs + (wn * 64 + i * 16 + ml) * 32 + q * 8);
        }
#pragma unroll
        for (int i = 0; i < 4; ++i)
#pragma unroll
            for (int j = 0; j < 4; ++j)
                acc[i][j] = __builtin_amdgcn_mfma_f32_16x16x32_bf16(a[i], b[j], acc[i][j], 0, 0, 0);
    }
#pragma unroll
    for (int i = 0; i < 4; ++i)
#pragma unroll
        for (int r = 0; r < 4; ++r) {
            int lr = wm * 64 + i * 16 + q * 4 + r;
            int tok = stok[lr];
            if (tok < 0) continue;
            size_t trow = (size_t)tok << 10;
#pragma unroll
            for (int j = 0; j < 4; ++j) {
                int h = h0 + wn * 64 + j * 16 + ml;
                atomicAdd(&out[trow + h], acc[i][j][r]);
            }
        }
}

// ===========================================================================
// ================= Fallback: proven round-3 path (~69 MB) ==================
#define SCAP3 1024
__global__ void router3_kernel(const int* __restrict__ te, const float* __restrict__ tw,
                               int* __restrict__ cnt_g, int* __restrict__ slot_tok,
                               float* __restrict__ slot_w) {
    __shared__ int cnt[E_];
    __shared__ int s_any;
    int tid = threadIdx.x;
    if (tid < E_) cnt[tid] = 0;
    if (tid == 0) s_any = 0;
    __syncthreads();
    int any = 0;
    for (int i = tid; i < 2 * T_; i += 256) if (i & 1) any |= te[i];
    if (any) atomicOr(&s_any, 1);
    __syncthreads();
    bool is32 = (s_any != 0);
    for (int t = tid; t < T_; t += 256) {
        int e0 = is32 ? te[2 * t]     : te[4 * t];
        int e1 = is32 ? te[2 * t + 1] : te[4 * t + 2];
        float w0 = tw[2 * t], w1 = tw[2 * t + 1];
        if (e0 == e1) {
            int p = atomicAdd(&cnt[e0], 1);
            if (p < SCAP3) { slot_tok[e0 * SCAP3 + p] = t; slot_w[e0 * SCAP3 + p] = w0 + w1; }
        } else {
            int p = atomicAdd(&cnt[e0], 1);
            if (p < SCAP3) { slot_tok[e0 * SCAP3 + p] = t; slot_w[e0 * SCAP3 + p] = w0; }
            p = atomicAdd(&cnt[e1], 1);
            if (p < SCAP3) { slot_tok[e1 * SCAP3 + p] = t; slot_w[e1 * SCAP3 + p] = w1; }
        }
    }
    __syncthreads();
    for (int e = 0; e < E_; ++e) {
        int c = min(cnt[e], SCAP3);
        int pc = min((c + 127) & ~127, SCAP3);
        for (int p = c + tid; p < pc; p += 256) {
            slot_tok[e * SCAP3 + p] = 0; slot_w[e * SCAP3 + p] = 0.f;
        }
    }
    if (tid < E_) cnt_g[tid] = min(cnt[tid], SCAP3);
}
__global__ __launch_bounds__(256, 2) void glu3_kernel(
        const u16* __restrict__ xb, const float* __restrict__ w1,
        const float* __restrict__ v1, const int* __restrict__ cnt_g,
        const int* __restrict__ slot_tok, const float* __restrict__ slot_w,
        u16* __restrict__ inter) {
    int e = blockIdx.x >> 3, tt = blockIdx.x & 7;
    if (tt * 128 >= cnt_g[e]) return;
    __shared__ __align__(16) u16 As[128 * 32];
    __shared__ __align__(16) u16 B1s[128 * 32];
    __shared__ __align__(16) u16 B2s[128 * 32];
    __shared__ int stok[128];
    __shared__ float sw[128];
    int tid = threadIdx.x;
    if (tid < 128) {
        stok[tid] = slot_tok[e * SCAP3 + tt * 128 + tid];
        sw[tid]   = slot_w[e * SCAP3 + tt * 128 + tid];
    }
    __syncthreads();
    int lane = tid & 63, wave = tid >> 6;
    int wm = wave >> 1, wn = wave & 1;
    int f0 = blockIdx.y * 128;
    int ml = lane & 15, q = lane >> 4;
    int r0 = tid >> 2, r1 = 64 + (tid >> 2);
    int colo = (tid & 3) * 8;
    const size_t tokoff0 = (size_t)stok[r0] * H_ + colo;
    const size_t tokoff1 = (size_t)stok[r1] * H_ + colo;
    const float* gb1 = w1 + (size_t)e * F_ * H_ + (size_t)f0 * H_;
    const float* gb2 = v1 + (size_t)e * F_ * H_ + (size_t)f0 * H_;
    const size_t boff0 = (size_t)r0 * H_ + colo;
    const size_t boff1 = (size_t)r1 * H_ + colo;
    f4v accg[4][4] = {};
    f4v accu[4][4] = {};
    for (int k0 = 0; k0 < H_; k0 += 32) {
        __syncthreads();
        *(int4*)(As + tid * 8)         = *(const int4*)(xb + tokoff0 + k0);
        *(int4*)(As + (256 + tid) * 8) = *(const int4*)(xb + tokoff1 + k0);
        const float* p = gb1 + boff0 + k0;
        *(int4*)(B1s + tid * 8) = cvt8(*(const float4*)p, *(const float4*)(p + 4));
        p = gb1 + boff1 + k0;
        *(int4*)(B1s + (256 + tid) * 8) = cvt8(*(const float4*)p, *(const float4*)(p + 4));
        p = gb2 + boff0 + k0;
        *(int4*)(B2s + tid * 8) = cvt8(*(const float4*)p, *(const float4*)(p + 4));
        p = gb2 + boff1 + k0;
        *(int4*)(B2s + (256 + tid) * 8) = cvt8(*(const float4*)p, *(const float4*)(p + 4));
        __syncthreads();
        s8v a[4], b1[4], b2[4];
#pragma unroll
        for (int i = 0; i < 4; ++i) {
            a[i]  = *(const s8v*)(As  + (wm * 64 + i * 16 + ml) * 32 + q * 8);
            b1[i] = *(const s8v*)(B1s + (wn * 64 + i * 16 + ml) * 32 + q * 8);
            b2[i] = *(const s8v*)(B2s + (wn * 64 + i * 16 + ml) * 32 + q * 8);
        }
#pragma unroll
        for (int i = 0; i < 4; ++i)
#pragma unroll
            for (int j = 0; j < 4; ++j) {
                accg[i][j] = __builtin_amdgcn_mfma_f32_16x16x32_bf16(a[i], b1[j], accg[i][j], 0, 0, 0);
                accu[i][j] = __builtin_amdgcn_mfma_f32_16x16x32_bf16(a[i], b2[j], accu[i][j], 0, 0, 0);
            }
    }
#pragma unroll
    for (int i = 0; i < 4; ++i)
#pragma unroll
        for (int r = 0; r < 4; ++r) {
            int lr = wm * 64 + i * 16 + q * 4 + r;
            float cv = sw[lr];
#pragma unroll
            for (int j = 0; j < 4; ++j) {
                float g = accg[i][j][r];
                float u = accu[i][j][r];
                float s = g / (1.f + __expf(-g));
                int f = f0 + wn * 64 + j * 16 + ml;
                inter[(size_t)(e * SCAP3 + tt * 128 + lr) * F_ + f] = f2bf(cv * s * u);
            }
        }
}
__global__ __launch_bounds__(256) void down3_kernel(
        const u16* __restrict__ inter, const u16* __restrict__ w2bT,
        const int* __restrict__ cnt_g, const int* __restrict__ slot_tok,
        float* __restrict__ out) {
    int e = blockIdx.x >> 3, tt = blockIdx.x & 7;
    if (tt * 128 >= cnt_g[e]) return;
    __shared__ __align__(16) u16 As[128 * 32];
    __shared__ __align__(16) u16 Bs[128 * 32];
    __shared__ int stok[128];
    int tid = threadIdx.x;
    if (tid < 128) stok[tid] = slot_tok[e * SCAP3 + tt * 128 + tid];
    __syncthreads();
    int lane = tid & 63, wave = tid >> 6;
    int wm = wave >> 1, wn = wave & 1;
    int h0 = blockIdx.y * 128;
    int ml = lane & 15, q = lane >> 4;
    int kbeg = blockIdx.z * (F_ / 2), kend = kbeg + (F_ / 2);
    f4v acc[4][4] = {};
    const u16* ga = inter + (size_t)(e * SCAP3 + tt * 128) * F_;
    const u16* gb = w2bT + (size_t)e * H_ * F_ + (size_t)h0 * F_;
    for (int k0 = kbeg; k0 < kend; k0 += 32) {
        __syncthreads();
#pragma unroll
        for (int p = 0; p < 2; ++p) {
            int c = p * 256 + tid;
            int r = c >> 2, co = (c & 3) * 8;
            *(int4*)(As + c * 8) = *(const int4*)(ga + (size_t)r * F_ + k0 + co);
            *(int4*)(Bs + c * 8) = *(const int4*)(gb + (size_t)r * F_ + k0 + co);
        }
        __syncthreads();
        s8v a[4], b[4];
#pragma unroll
        for (int i = 0; i < 4; ++i) {
            a[i] = *(const s8v*)(As + (wm * 64 + i * 16 + ml) * 32 + q * 8);
            b[i] = *(const s8v*)(Bs + (wn * 64 + i * 16 + ml) * 32 + q * 8);
        }
#pragma unroll
        for (int i = 0; i < 4; ++i)
#pragma unroll
            for (int j = 0; j < 4; ++j)
                acc[i][j] = __builtin_amdgcn_mfma_f32_16x16x32_bf16(a[i], b[j], acc[i][j], 0, 0, 0);
    }
#pragma unroll
    for (int i = 0; i < 4; ++i)
#pragma unroll
        for (int r = 0; r < 4; ++r) {
            int lr = wm * 64 + i * 16 + q * 4 + r;
            size_t trow = (size_t)stok[lr] * H_;
#pragma unroll
            for (int j = 0; j < 4; ++j) {
                int h = h0 + wn * 64 + j * 16 + ml;
                atomicAdd(&out[trow + h], acc[i][j][r]);
            }
        }
}

// ===========================================================================
extern "C" void kernel_launch(void* const* d_in, const int* in_sizes, int n_in,
                              void* d_out, int out_size, void* d_ws, size_t ws_size,
                              hipStream_t stream) {
    const float* x  = (const float*)d_in[0];
    const float* tw = (const float*)d_in[2];
    const int*   te = (const int*)d_in[3];
    const float* w1 = (const float*)d_in[4];
    const float* v1 = (const float*)d_in[5];
    const float* w2 = (const float*)d_in[6];
    float* out = (float*)d_out;
    char* ws = (char*)d_ws;

    if (ws_size >= ((size_t)135 << 20)) {
        // ---- primary async path (~133 MiB) ----
        int*   tile_e   = (int*)(ws + (1 << 10));
        int*   tile_s   = (int*)(ws + (2 << 10));
        int*   ntiles   = (int*)(ws + 256);
        int*   slot_tok = (int*)(ws + (4 << 10));
        float* slot_w   = (float*)(ws + (32 << 10));
        u16*   xg       = (u16*)(ws + ((size_t)1 << 20));
        u16*   w1b      = (u16*)(ws + ((size_t)13 << 20));
        u16*   v1b      = (u16*)(ws + ((size_t)45 << 20));
        u16*   w2bT     = (u16*)(ws + ((size_t)77 << 20));
        u16*   inter    = (u16*)(ws + ((size_t)109 << 20));

        hipMemsetAsync(out, 0, (size_t)T_ * H_ * sizeof(float), stream);
        router_kernel<<<1, 256, 0, stream>>>(te, tw, slot_tok, slot_w, tile_e, tile_s, ntiles);
        cvt_kernel<<<(E_ * F_ * H_) / 1024, 256, 0, stream>>>(w1, w1b);
        cvt_kernel<<<(E_ * F_ * H_) / 1024, 256, 0, stream>>>(v1, v1b);
        tcvt8_kernel<<<dim3(H_ / 64, F_ / 64, E_), dim3(8, 32), 0, stream>>>(w2, w2bT);
        gather_x_kernel<<<MAXT2, 256, 0, stream>>>(x, slot_tok, tile_s, ntiles, xg);
        glu_async_kernel<<<dim3(F_ / 128, MAXT2), 256, 0, stream>>>(
            xg, w1b, v1b, tile_e, tile_s, ntiles, slot_w, inter);
        down_async_kernel<<<dim3(H_ / 128, MAXT2, 2), 256, 0, stream>>>(
            inter, w2bT, tile_e, tile_s, ntiles, slot_tok, out);
    } else {
        // ---- fallback: round-3 path (~69 MB, proven) ----
        int*   cnt_g    = (int*)(ws);
        int*   slot_tok = (int*)(ws + (4 << 10));
        float* slot_w   = (float*)(ws + (64 << 10));
        u16*   xb       = (u16*)(ws + ((size_t)1 << 20));
        u16*   w2bT     = (u16*)(ws + ((size_t)5 << 20));
        u16*   inter    = (u16*)(ws + ((size_t)37 << 20));

        hipMemsetAsync(out, 0, (size_t)T_ * H_ * sizeof(float), stream);
        router3_kernel<<<1, 256, 0, stream>>>(te, tw, cnt_g, slot_tok, slot_w);
        cvt_kernel<<<(T_ * H_) / 1024, 256, 0, stream>>>(x, xb);
        tcvt8_kernel<<<dim3(H_ / 64, F_ / 64, E_), dim3(8, 32), 0, stream>>>(w2, w2bT);
        glu3_kernel<<<dim3(E_ * 8, F_ / 128), 256, 0, stream>>>(
            xb, w1, v1, cnt_g, slot_tok, slot_w, inter);
        down3_kernel<<<dim3(E_ * 8, H_ / 128, 2), 256, 0, stream>>>(
            inter, w2bT, cnt_g, slot_tok, out);
    }
}

// Round 6
// 367.494 us; speedup vs baseline: 2.5858x; 1.0186x over previous
//
#include <hip/hip_runtime.h>
#include <hip/hip_bf16.h>

// DBRX MoE experts forward, MI355X gfx950.
// T=2048, H=1024, F=2048, E=8, K=2. f32 storage in/out; bf16 MFMA compute.
// Round 6: N=64 tiles (4 blocks/CU for latency overlap), atomic-free down
// (K-split x2 into disjoint f32 buffers + per-token combine), fused weight
// converts, XCD-aware grid order for L2 weight reuse, async global_load_lds
// staging. Fallback to proven round-3 path if ws_size < 135 MiB.

#define T_ 2048
#define H_ 1024
#define F_ 2048
#define E_ 8

#define SCAP 768                  // per-expert slot capacity (multiple of 128)
#define NSLOT (E_ * SCAP)         // 6144
#define MAXT2 (NSLOT / 128)       // 48 max 128-slot tiles

typedef unsigned short u16;
typedef short s8v __attribute__((ext_vector_type(8)));
typedef float f4v __attribute__((ext_vector_type(4)));
typedef unsigned short u16x4 __attribute__((ext_vector_type(4)));

__device__ __forceinline__ u16 f2bf(float f) {
    union { float f; unsigned u; } v; v.f = f;
    unsigned r = v.u + 0x7FFF + ((v.u >> 16) & 1);   // RNE
    return (u16)(r >> 16);
}
__device__ __forceinline__ unsigned pkbf(float a, float b) {
    __hip_bfloat162 h = __float22bfloat162_rn(make_float2(a, b));
    union { __hip_bfloat162 h; unsigned u; } c; c.h = h; return c.u;
}
__device__ __forceinline__ int4 cvt8(const float4 a, const float4 b) {
    int4 r; r.x = (int)pkbf(a.x, a.y); r.y = (int)pkbf(a.z, a.w);
    r.z = (int)pkbf(b.x, b.y); r.w = (int)pkbf(b.z, b.w); return r;
}
// async 16B/lane global->LDS; staging geometry keeps per-lane LDS addr ==
// wave base + lane*16 (row = wb + lane/4, col = (lane&3)*8 over 64B rows).
__device__ __forceinline__ void async16(void* lds, const void* g) {
    __builtin_amdgcn_global_load_lds(
        (const __attribute__((address_space(1))) unsigned*)g,
        (__attribute__((address_space(3))) unsigned*)lds, 16, 0, 0);
}

// ===========================================================================
// Router: per-expert (token, weight) lists padded to x128 (tok=-1, w=0),
// tile table (128-slot tiles), and per-token slot map tok_slot[t][k]
// (k-slot 1 = -1 when merged into slot 0, or on overflow).
__global__ void router_kernel(const int* __restrict__ te, const float* __restrict__ tw,
                              int* __restrict__ slot_tok, float* __restrict__ slot_w,
                              int* __restrict__ tok_slot,
                              int* __restrict__ tile_e, int* __restrict__ tile_s,
                              int* __restrict__ ntiles) {
    __shared__ int cnt[E_];
    __shared__ int s_any;
    int tid = threadIdx.x;
    if (tid < E_) cnt[tid] = 0;
    if (tid == 0) s_any = 0;
    __syncthreads();
    int any = 0;
    for (int i = tid; i < 2 * T_; i += 256) if (i & 1) any |= te[i];
    if (any) atomicOr(&s_any, 1);
    __syncthreads();
    bool is32 = (s_any != 0);      // int64 storage -> odd words all zero
    for (int t = tid; t < T_; t += 256) {
        int e0 = is32 ? te[2 * t]     : te[4 * t];
        int e1 = is32 ? te[2 * t + 1] : te[4 * t + 2];
        float w0 = tw[2 * t], w1 = tw[2 * t + 1];
        if (e0 == e1) {
            int p = atomicAdd(&cnt[e0], 1);
            int s = (p < SCAP) ? e0 * SCAP + p : -1;
            if (s >= 0) { slot_tok[s] = t; slot_w[s] = w0 + w1; }
            tok_slot[2 * t] = s; tok_slot[2 * t + 1] = -1;
        } else {
            int p = atomicAdd(&cnt[e0], 1);
            int s = (p < SCAP) ? e0 * SCAP + p : -1;
            if (s >= 0) { slot_tok[s] = t; slot_w[s] = w0; }
            tok_slot[2 * t] = s;
            p = atomicAdd(&cnt[e1], 1);
            s = (p < SCAP) ? e1 * SCAP + p : -1;
            if (s >= 0) { slot_tok[s] = t; slot_w[s] = w1; }
            tok_slot[2 * t + 1] = s;
        }
    }
    __syncthreads();
    for (int e = 0; e < E_; ++e) {
        int c = min(cnt[e], SCAP);
        int pc = min((c + 127) & ~127, SCAP);
        for (int p = c + tid; p < pc; p += 256) {
            slot_tok[e * SCAP + p] = -1; slot_w[e * SCAP + p] = 0.f;
        }
    }
    __syncthreads();
    if (tid == 0) {
        int nt = 0;
        for (int e = 0; e < E_; ++e) {
            int pc = min((min(cnt[e], SCAP) + 127) & ~127, SCAP);
            for (int s = 0; s < pc; s += 128) { tile_e[nt] = e; tile_s[nt] = e * SCAP + s; ++nt; }
        }
        *ntiles = nt;
    }
}

// Fused f32->bf16 for w1 (y=0) and v1 (y=1), 4 elems/thread.
__global__ void cvtwv_kernel(const float* __restrict__ w1, const float* __restrict__ v1,
                             u16* __restrict__ w1b, u16* __restrict__ v1b) {
    const float* src = blockIdx.y ? v1 : w1;
    u16* dst = blockIdx.y ? v1b : w1b;
    int i = (blockIdx.x * 256 + threadIdx.x) * 4;
    float4 v = *(const float4*)(src + i);
    u16x4 o = { f2bf(v.x), f2bf(v.y), f2bf(v.z), f2bf(v.w) };
    *(u16x4*)(dst + i) = o;
}

// f32 [F][H] -> bf16 [H][F] per expert (blockIdx.z), 64x64 tiles.
__global__ void tcvt8_kernel(const float* __restrict__ src0, u16* __restrict__ dst0) {
    const float* src = src0 + (size_t)blockIdx.z * F_ * H_;
    u16* dst = dst0 + (size_t)blockIdx.z * H_ * F_;
    __shared__ __align__(16) u16 tile[64][72];
    int bc = blockIdx.x * 64, br = blockIdx.y * 64;
    int tx = threadIdx.x, ty = threadIdx.y;   // (8,32)
    for (int r = ty; r < 64; r += 32) {
        const float* p = src + (size_t)(br + r) * H_ + bc + tx * 8;
        float4 v0 = *(const float4*)p;
        float4 v1 = *(const float4*)(p + 4);
        u16* q = &tile[r][tx * 8];
        q[0] = f2bf(v0.x); q[1] = f2bf(v0.y); q[2] = f2bf(v0.z); q[3] = f2bf(v0.w);
        q[4] = f2bf(v1.x); q[5] = f2bf(v1.y); q[6] = f2bf(v1.z); q[7] = f2bf(v1.w);
    }
    __syncthreads();
    for (int c = ty; c < 64; c += 32) {
        u16 tmp[8];
#pragma unroll
        for (int j = 0; j < 8; ++j) tmp[j] = tile[tx * 8 + j][c];
        *(int4*)&dst[(size_t)(bc + c) * F_ + br + tx * 8] = *(int4*)tmp;
    }
}

// Gather+convert x rows into slot order: xg[slot][H] = bf16(x[tok]); zeros
// for sentinels. One block per 128-slot tile.
__global__ void gather_x_kernel(const float* __restrict__ x, const int* __restrict__ slot_tok,
                                const int* __restrict__ tile_s, const int* __restrict__ ntiles,
                                u16* __restrict__ xg) {
    if ((int)blockIdx.x >= *ntiles) return;
    int base = tile_s[blockIdx.x];
    int tid = threadIdx.x;
    __shared__ int stok[128];
    if (tid < 128) stok[tid] = slot_tok[base + tid];
    __syncthreads();
    for (int c = tid; c < 128 * 128; c += 256) {      // 8-elem chunks
        int r = c >> 7, co = (c & 127) * 8;
        int tok = stok[r];
        u16* dst = xg + ((size_t)(base + r) << 10) + co;
        if (tok < 0) { *(int4*)dst = make_int4(0, 0, 0, 0); }
        else {
            const float* p = x + ((size_t)tok << 10) + co;
            *(int4*)dst = cvt8(*(const float4*)p, *(const float4*)(p + 4));
        }
    }
}

// ===========================================================================
// GLU GEMM: 128(slots) x 64(f), BK=32, async staging, dual acc.
// grid = (f-tile 32, token-tile 48): same-(e,f0) blocks spaced 32 apart ->
// same XCD (id%8) -> weight tiles served from L2; A re-reads L3-absorbed.
__global__ __launch_bounds__(256, 4) void glu_async_kernel(
        const u16* __restrict__ xg, const u16* __restrict__ w1b,
        const u16* __restrict__ v1b, const int* __restrict__ tile_e,
        const int* __restrict__ tile_s, const int* __restrict__ ntiles,
        const float* __restrict__ slot_w, u16* __restrict__ inter) {
    int bt = blockIdx.y;
    if (bt >= *ntiles) return;
    int e = tile_e[bt], s0 = tile_s[bt];
    int f0 = blockIdx.x * 64;
    __shared__ __align__(16) u16 As[128 * 32];
    __shared__ __align__(16) u16 B1s[64 * 32];
    __shared__ __align__(16) u16 B2s[64 * 32];
    __shared__ float swv[128];
    int tid = threadIdx.x;
    int lane = tid & 63, wave = tid >> 6;
    int wm = wave >> 1, wn = wave & 1;
    int ml = lane & 15, q = lane >> 4;
    if (tid < 128) swv[tid] = slot_w[s0 + tid];

    int acol = (lane & 3) << 3;
    int row0 = (wave << 4) + (lane >> 2);            // 0..63
    int row1 = row0 + 64;
    const u16* gA0  = xg + ((size_t)(s0 + row0) << 10) + acol;
    const u16* gA1  = xg + ((size_t)(s0 + row1) << 10) + acol;
    const size_t wofs = (size_t)e * F_ * H_;
    const u16* gB1 = w1b + wofs + ((size_t)(f0 + row0) << 10) + acol;
    const u16* gB2 = v1b + wofs + ((size_t)(f0 + row0) << 10) + acol;
    u16* lA0 = As  + (row0 << 5) + acol;
    u16* lA1 = As  + (row1 << 5) + acol;
    u16* lB1 = B1s + (row0 << 5) + acol;
    u16* lB2 = B2s + (row0 << 5) + acol;

    f4v accg[4][2] = {};
    f4v accu[4][2] = {};

    for (int k0 = 0; k0 < H_; k0 += 32) {
        __syncthreads();
        async16(lA0, gA0 + k0);
        async16(lA1, gA1 + k0);
        async16(lB1, gB1 + k0);
        async16(lB2, gB2 + k0);
        __syncthreads();
        s8v a[4], b1[2], b2[2];
#pragma unroll
        for (int i = 0; i < 4; ++i)
            a[i]  = *(const s8v*)(As  + (wm * 64 + i * 16 + ml) * 32 + q * 8);
#pragma unroll
        for (int j = 0; j < 2; ++j) {
            b1[j] = *(const s8v*)(B1s + (wn * 32 + j * 16 + ml) * 32 + q * 8);
            b2[j] = *(const s8v*)(B2s + (wn * 32 + j * 16 + ml) * 32 + q * 8);
        }
#pragma unroll
        for (int i = 0; i < 4; ++i)
#pragma unroll
            for (int j = 0; j < 2; ++j) {
                accg[i][j] = __builtin_amdgcn_mfma_f32_16x16x32_bf16(a[i], b1[j], accg[i][j], 0, 0, 0);
                accu[i][j] = __builtin_amdgcn_mfma_f32_16x16x32_bf16(a[i], b2[j], accu[i][j], 0, 0, 0);
            }
    }
#pragma unroll
    for (int i = 0; i < 4; ++i)
#pragma unroll
        for (int r = 0; r < 4; ++r) {
            int lr = wm * 64 + i * 16 + q * 4 + r;
            float cv = swv[lr];
#pragma unroll
            for (int j = 0; j < 2; ++j) {
                float g = accg[i][j][r];
                float u = accu[i][j][r];
                float s = g / (1.f + __expf(-g));
                int f = f0 + wn * 32 + j * 16 + ml;
                inter[((size_t)(s0 + lr) << 11) + f] = f2bf(cv * s * u);
            }
        }
}

// Down GEMM: 128(slots) x 64(h), K=F split x2 into DISJOINT f32 buffers
// (slot-indexed, no atomics). grid = (h-tile 16, token-tile 48, ksplit 2).
__global__ __launch_bounds__(256, 4) void down_async_kernel(
        const u16* __restrict__ inter, const u16* __restrict__ w2bT,
        const int* __restrict__ tile_e, const int* __restrict__ tile_s,
        const int* __restrict__ ntiles,
        float* __restrict__ dbufA, float* __restrict__ dbufB) {
    int bt = blockIdx.y;
    if (bt >= *ntiles) return;
    int e = tile_e[bt], s0 = tile_s[bt];
    int h0 = blockIdx.x * 64;
    int ks = blockIdx.z;
    int kbeg = ks * (F_ / 2);
    float* dbuf = ks ? dbufB : dbufA;
    __shared__ __align__(16) u16 As[128 * 32];
    __shared__ __align__(16) u16 Bs[64 * 32];
    int tid = threadIdx.x;
    int lane = tid & 63, wave = tid >> 6;
    int wm = wave >> 1, wn = wave & 1;
    int ml = lane & 15, q = lane >> 4;

    int acol = (lane & 3) << 3;
    int row0 = (wave << 4) + (lane >> 2);
    int row1 = row0 + 64;
    const u16* gA0 = inter + ((size_t)(s0 + row0) << 11) + kbeg + acol;
    const u16* gA1 = inter + ((size_t)(s0 + row1) << 11) + kbeg + acol;
    const u16* gB  = w2bT + (size_t)e * H_ * F_ + ((size_t)(h0 + row0) << 11) + kbeg + acol;
    u16* lA0 = As + (row0 << 5) + acol;
    u16* lA1 = As + (row1 << 5) + acol;
    u16* lB  = Bs + (row0 << 5) + acol;

    f4v acc[4][2] = {};
    for (int k0 = 0; k0 < F_ / 2; k0 += 32) {
        __syncthreads();
        async16(lA0, gA0 + k0);
        async16(lA1, gA1 + k0);
        async16(lB,  gB  + k0);
        __syncthreads();
        s8v a[4], b[2];
#pragma unroll
        for (int i = 0; i < 4; ++i)
            a[i] = *(const s8v*)(As + (wm * 64 + i * 16 + ml) * 32 + q * 8);
#pragma unroll
        for (int j = 0; j < 2; ++j)
            b[j] = *(const s8v*)(Bs + (wn * 32 + j * 16 + ml) * 32 + q * 8);
#pragma unroll
        for (int i = 0; i < 4; ++i)
#pragma unroll
            for (int j = 0; j < 2; ++j)
                acc[i][j] = __builtin_amdgcn_mfma_f32_16x16x32_bf16(a[i], b[j], acc[i][j], 0, 0, 0);
    }
#pragma unroll
    for (int i = 0; i < 4; ++i)
#pragma unroll
        for (int r = 0; r < 4; ++r) {
            int lr = wm * 64 + i * 16 + q * 4 + r;
            float* drow = dbuf + ((size_t)(s0 + lr) << 10);
#pragma unroll
            for (int j = 0; j < 2; ++j) {
                int h = h0 + wn * 32 + j * 16 + ml;
                drow[h] = acc[i][j][r];
            }
        }
}

// out[t][h] = sum over token's <=2 slots of (dbufA+dbufB). One block/token.
__global__ void combine_kernel(const float* __restrict__ dbufA, const float* __restrict__ dbufB,
                               const int* __restrict__ tok_slot, float* __restrict__ out) {
    int t = blockIdx.x;
    int c = threadIdx.x * 4;
    int s0 = tok_slot[2 * t], s1 = tok_slot[2 * t + 1];
    float4 acc = make_float4(0.f, 0.f, 0.f, 0.f);
    if (s0 >= 0) {
        float4 a = *(const float4*)(dbufA + ((size_t)s0 << 10) + c);
        float4 b = *(const float4*)(dbufB + ((size_t)s0 << 10) + c);
        acc.x = a.x + b.x; acc.y = a.y + b.y; acc.z = a.z + b.z; acc.w = a.w + b.w;
    }
    if (s1 >= 0) {
        float4 a = *(const float4*)(dbufA + ((size_t)s1 << 10) + c);
        float4 b = *(const float4*)(dbufB + ((size_t)s1 << 10) + c);
        acc.x += a.x + b.x; acc.y += a.y + b.y; acc.z += a.z + b.z; acc.w += a.w + b.w;
    }
    *(float4*)(out + ((size_t)t << 10) + c) = acc;
}

// ===========================================================================
// ================= Fallback: proven round-3 path (~69 MB) ==================
#define SCAP3 1024
__global__ void router3_kernel(const int* __restrict__ te, const float* __restrict__ tw,
                               int* __restrict__ cnt_g, int* __restrict__ slot_tok,
                               float* __restrict__ slot_w) {
    __shared__ int cnt[E_];
    __shared__ int s_any;
    int tid = threadIdx.x;
    if (tid < E_) cnt[tid] = 0;
    if (tid == 0) s_any = 0;
    __syncthreads();
    int any = 0;
    for (int i = tid; i < 2 * T_; i += 256) if (i & 1) any |= te[i];
    if (any) atomicOr(&s_any, 1);
    __syncthreads();
    bool is32 = (s_any != 0);
    for (int t = tid; t < T_; t += 256) {
        int e0 = is32 ? te[2 * t]     : te[4 * t];
        int e1 = is32 ? te[2 * t + 1] : te[4 * t + 2];
        float w0 = tw[2 * t], w1 = tw[2 * t + 1];
        if (e0 == e1) {
            int p = atomicAdd(&cnt[e0], 1);
            if (p < SCAP3) { slot_tok[e0 * SCAP3 + p] = t; slot_w[e0 * SCAP3 + p] = w0 + w1; }
        } else {
            int p = atomicAdd(&cnt[e0], 1);
            if (p < SCAP3) { slot_tok[e0 * SCAP3 + p] = t; slot_w[e0 * SCAP3 + p] = w0; }
            p = atomicAdd(&cnt[e1], 1);
            if (p < SCAP3) { slot_tok[e1 * SCAP3 + p] = t; slot_w[e1 * SCAP3 + p] = w1; }
        }
    }
    __syncthreads();
    for (int e = 0; e < E_; ++e) {
        int c = min(cnt[e], SCAP3);
        int pc = min((c + 127) & ~127, SCAP3);
        for (int p = c + tid; p < pc; p += 256) {
            slot_tok[e * SCAP3 + p] = 0; slot_w[e * SCAP3 + p] = 0.f;
        }
    }
    if (tid < E_) cnt_g[tid] = min(cnt[tid], SCAP3);
}
__global__ void cvt_kernel(const float* __restrict__ src, u16* __restrict__ dst) {
    int i = (blockIdx.x * 256 + threadIdx.x) * 4;
    float4 v = *(const float4*)(src + i);
    u16x4 o = { f2bf(v.x), f2bf(v.y), f2bf(v.z), f2bf(v.w) };
    *(u16x4*)(dst + i) = o;
}
__global__ __launch_bounds__(256, 2) void glu3_kernel(
        const u16* __restrict__ xb, const float* __restrict__ w1,
        const float* __restrict__ v1, const int* __restrict__ cnt_g,
        const int* __restrict__ slot_tok, const float* __restrict__ slot_w,
        u16* __restrict__ inter) {
    int e = blockIdx.x >> 3, tt = blockIdx.x & 7;
    if (tt * 128 >= cnt_g[e]) return;
    __shared__ __align__(16) u16 As[128 * 32];
    __shared__ __align__(16) u16 B1s[128 * 32];
    __shared__ __align__(16) u16 B2s[128 * 32];
    __shared__ int stok[128];
    __shared__ float sw[128];
    int tid = threadIdx.x;
    if (tid < 128) {
        stok[tid] = slot_tok[e * SCAP3 + tt * 128 + tid];
        sw[tid]   = slot_w[e * SCAP3 + tt * 128 + tid];
    }
    __syncthreads();
    int lane = tid & 63, wave = tid >> 6;
    int wm = wave >> 1, wn = wave & 1;
    int f0 = blockIdx.y * 128;
    int ml = lane & 15, q = lane >> 4;
    int r0 = tid >> 2, r1 = 64 + (tid >> 2);
    int colo = (tid & 3) * 8;
    const size_t tokoff0 = (size_t)stok[r0] * H_ + colo;
    const size_t tokoff1 = (size_t)stok[r1] * H_ + colo;
    const float* gb1 = w1 + (size_t)e * F_ * H_ + (size_t)f0 * H_;
    const float* gb2 = v1 + (size_t)e * F_ * H_ + (size_t)f0 * H_;
    const size_t boff0 = (size_t)r0 * H_ + colo;
    const size_t boff1 = (size_t)r1 * H_ + colo;
    f4v accg[4][4] = {};
    f4v accu[4][4] = {};
    for (int k0 = 0; k0 < H_; k0 += 32) {
        __syncthreads();
        *(int4*)(As + tid * 8)         = *(const int4*)(xb + tokoff0 + k0);
        *(int4*)(As + (256 + tid) * 8) = *(const int4*)(xb + tokoff1 + k0);
        const float* p = gb1 + boff0 + k0;
        *(int4*)(B1s + tid * 8) = cvt8(*(const float4*)p, *(const float4*)(p + 4));
        p = gb1 + boff1 + k0;
        *(int4*)(B1s + (256 + tid) * 8) = cvt8(*(const float4*)p, *(const float4*)(p + 4));
        p = gb2 + boff0 + k0;
        *(int4*)(B2s + tid * 8) = cvt8(*(const float4*)p, *(const float4*)(p + 4));
        p = gb2 + boff1 + k0;
        *(int4*)(B2s + (256 + tid) * 8) = cvt8(*(const float4*)p, *(const float4*)(p + 4));
        __syncthreads();
        s8v a[4], b1[4], b2[4];
#pragma unroll
        for (int i = 0; i < 4; ++i) {
            a[i]  = *(const s8v*)(As  + (wm * 64 + i * 16 + ml) * 32 + q * 8);
            b1[i] = *(const s8v*)(B1s + (wn * 64 + i * 16 + ml) * 32 + q * 8);
            b2[i] = *(const s8v*)(B2s + (wn * 64 + i * 16 + ml) * 32 + q * 8);
        }
#pragma unroll
        for (int i = 0; i < 4; ++i)
#pragma unroll
            for (int j = 0; j < 4; ++j) {
                accg[i][j] = __builtin_amdgcn_mfma_f32_16x16x32_bf16(a[i], b1[j], accg[i][j], 0, 0, 0);
                accu[i][j] = __builtin_amdgcn_mfma_f32_16x16x32_bf16(a[i], b2[j], accu[i][j], 0, 0, 0);
            }
    }
#pragma unroll
    for (int i = 0; i < 4; ++i)
#pragma unroll
        for (int r = 0; r < 4; ++r) {
            int lr = wm * 64 + i * 16 + q * 4 + r;
            float cv = sw[lr];
#pragma unroll
            for (int j = 0; j < 4; ++j) {
                float g = accg[i][j][r];
                float u = accu[i][j][r];
                float s = g / (1.f + __expf(-g));
                int f = f0 + wn * 64 + j * 16 + ml;
                inter[(size_t)(e * SCAP3 + tt * 128 + lr) * F_ + f] = f2bf(cv * s * u);
            }
        }
}
__global__ __launch_bounds__(256) void down3_kernel(
        const u16* __restrict__ inter, const u16* __restrict__ w2bT,
        const int* __restrict__ cnt_g, const int* __restrict__ slot_tok,
        float* __restrict__ out) {
    int e = blockIdx.x >> 3, tt = blockIdx.x & 7;
    if (tt * 128 >= cnt_g[e]) return;
    __shared__ __align__(16) u16 As[128 * 32];
    __shared__ __align__(16) u16 Bs[128 * 32];
    __shared__ int stok[128];
    int tid = threadIdx.x;
    if (tid < 128) stok[tid] = slot_tok[e * SCAP3 + tt * 128 + tid];
    __syncthreads();
    int lane = tid & 63, wave = tid >> 6;
    int wm = wave >> 1, wn = wave & 1;
    int h0 = blockIdx.y * 128;
    int ml = lane & 15, q = lane >> 4;
    int kbeg = blockIdx.z * (F_ / 2), kend = kbeg + (F_ / 2);
    f4v acc[4][4] = {};
    const u16* ga = inter + (size_t)(e * SCAP3 + tt * 128) * F_;
    const u16* gb = w2bT + (size_t)e * H_ * F_ + (size_t)h0 * F_;
    for (int k0 = kbeg; k0 < kend; k0 += 32) {
        __syncthreads();
#pragma unroll
        for (int p = 0; p < 2; ++p) {
            int c = p * 256 + tid;
            int r = c >> 2, co = (c & 3) * 8;
            *(int4*)(As + c * 8) = *(const int4*)(ga + (size_t)r * F_ + k0 + co);
            *(int4*)(Bs + c * 8) = *(const int4*)(gb + (size_t)r * F_ + k0 + co);
        }
        __syncthreads();
        s8v a[4], b[4];
#pragma unroll
        for (int i = 0; i < 4; ++i) {
            a[i] = *(const s8v*)(As + (wm * 64 + i * 16 + ml) * 32 + q * 8);
            b[i] = *(const s8v*)(Bs + (wn * 64 + i * 16 + ml) * 32 + q * 8);
        }
#pragma unroll
        for (int i = 0; i < 4; ++i)
#pragma unroll
            for (int j = 0; j < 4; ++j)
                acc[i][j] = __builtin_amdgcn_mfma_f32_16x16x32_bf16(a[i], b[j], acc[i][j], 0, 0, 0);
    }
#pragma unroll
    for (int i = 0; i < 4; ++i)
#pragma unroll
        for (int r = 0; r < 4; ++r) {
            int lr = wm * 64 + i * 16 + q * 4 + r;
            size_t trow = (size_t)stok[lr] * H_;
#pragma unroll
            for (int j = 0; j < 4; ++j) {
                int h = h0 + wn * 64 + j * 16 + ml;
                atomicAdd(&out[trow + h], acc[i][j][r]);
            }
        }
}

// ===========================================================================
extern "C" void kernel_launch(void* const* d_in, const int* in_sizes, int n_in,
                              void* d_out, int out_size, void* d_ws, size_t ws_size,
                              hipStream_t stream) {
    const float* x  = (const float*)d_in[0];
    const float* tw = (const float*)d_in[2];
    const int*   te = (const int*)d_in[3];
    const float* w1 = (const float*)d_in[4];
    const float* v1 = (const float*)d_in[5];
    const float* w2 = (const float*)d_in[6];
    float* out = (float*)d_out;
    char* ws = (char*)d_ws;

    if (ws_size >= ((size_t)135 << 20)) {
        // ---- primary async path (~134 MiB) ----
        // meta: ntiles@0, tile_e@256, tile_s@512, tok_slot@4K(16K),
        //       slot_tok@20K(24K), slot_w@44K(24K)
        // xg@1M(12M) | w1b@13M(32M) | v1b@45M(32M) | w2bT@77M(32M) | inter@109M(24M)
        // dbufA/B (f32, 24M each) overlay w1b/v1b after glu is done with them.
        int*   ntiles   = (int*)(ws);
        int*   tile_e   = (int*)(ws + 256);
        int*   tile_s   = (int*)(ws + 512);
        int*   tok_slot = (int*)(ws + (4 << 10));
        int*   slot_tok = (int*)(ws + (20 << 10));
        float* slot_w   = (float*)(ws + (44 << 10));
        u16*   xg       = (u16*)(ws + ((size_t)1 << 20));
        u16*   w1b      = (u16*)(ws + ((size_t)13 << 20));
        u16*   v1b      = (u16*)(ws + ((size_t)45 << 20));
        u16*   w2bT     = (u16*)(ws + ((size_t)77 << 20));
        u16*   inter    = (u16*)(ws + ((size_t)109 << 20));
        float* dbufA    = (float*)(ws + ((size_t)13 << 20));   // 25.2 MB
        float* dbufB    = (float*)(ws + ((size_t)45 << 20));   // 25.2 MB

        router_kernel<<<1, 256, 0, stream>>>(te, tw, slot_tok, slot_w, tok_slot,
                                             tile_e, tile_s, ntiles);
        cvtwv_kernel<<<dim3((E_ * F_ * H_) / 1024, 2), 256, 0, stream>>>(w1, v1, w1b, v1b);
        tcvt8_kernel<<<dim3(H_ / 64, F_ / 64, E_), dim3(8, 32), 0, stream>>>(w2, w2bT);
        gather_x_kernel<<<MAXT2, 256, 0, stream>>>(x, slot_tok, tile_s, ntiles, xg);
        glu_async_kernel<<<dim3(F_ / 64, MAXT2), 256, 0, stream>>>(
            xg, w1b, v1b, tile_e, tile_s, ntiles, slot_w, inter);
        down_async_kernel<<<dim3(H_ / 64, MAXT2, 2), 256, 0, stream>>>(
            inter, w2bT, tile_e, tile_s, ntiles, dbufA, dbufB);
        combine_kernel<<<T_, 256, 0, stream>>>(dbufA, dbufB, tok_slot, out);
    } else {
        // ---- fallback: round-3 path (~69 MB, proven) ----
        int*   cnt_g    = (int*)(ws);
        int*   slot_tok = (int*)(ws + (4 << 10));
        float* slot_w   = (float*)(ws + (64 << 10));
        u16*   xb       = (u16*)(ws + ((size_t)1 << 20));
        u16*   w2bT     = (u16*)(ws + ((size_t)5 << 20));
        u16*   inter    = (u16*)(ws + ((size_t)37 << 20));

        hipMemsetAsync(out, 0, (size_t)T_ * H_ * sizeof(float), stream);
        router3_kernel<<<1, 256, 0, stream>>>(te, tw, cnt_g, slot_tok, slot_w);
        cvt_kernel<<<(T_ * H_) / 1024, 256, 0, stream>>>(x, xb);
        tcvt8_kernel<<<dim3(H_ / 64, F_ / 64, E_), dim3(8, 32), 0, stream>>>(w2, w2bT);
        glu3_kernel<<<dim3(E_ * 8, F_ / 128), 256, 0, stream>>>(
            xb, w1, v1, cnt_g, slot_tok, slot_w, inter);
        down3_kernel<<<dim3(E_ * 8, H_ / 128, 2), 256, 0, stream>>>(
            inter, w2bT, cnt_g, slot_tok, out);
    }
}